// Round 7
// baseline (408.656 us; speedup 1.0000x reference)
//
#include <hip/hip_runtime.h>
#include <hip/hip_cooperative_groups.h>
#include <math.h>

namespace cg = cooperative_groups;

namespace {
constexpr int Bn = 2, Sn = 2048, INn = 512, HDn = 32, Hn = 16;
constexpr int NQ = Bn * Hn * Sn * HDn;           // 2097152 bf16 elems per Q/K/V tensor
// ws offsets in FLOAT units — all regions DISJOINT
constexpr int OFF_WLA = 0;          // Wl A-frags bf16: 4194304 bf16 -> 2097152 fl
constexpr int OFF_WXB = 2097152;    // Wq/k/v B-frags bf16: 786432 bf16 -> 393216 fl
constexpr int OFF_WBB = 2490368;    // Weff B-frags bf16: 786432 bf16 -> 393216 fl
constexpr int OFF_BEFF = 2883584;   // 1536 fl
constexpr int OFF_QKV = 2885120;    // Q,K,V swizzled bf16: 3*2097152 -> 3145728 fl
constexpr int OFF_XB = 6030848;     // x A-frags bf16 -> 1048576 fl
constexpr int OFF_FB = 7079424;     // F A-frags bf16 -> 1048576 fl
constexpr int OFF_WOB = 8128000;    // Wo B-frags bf16 -> 131072 fl
constexpr float LOG2E = 1.44269504f;
}

typedef __attribute__((ext_vector_type(8))) short s8v;   // 8 bf16 in 4 VGPRs
typedef __attribute__((ext_vector_type(4))) float f4v;   // MFMA accumulator

__device__ __forceinline__ unsigned short f2bf(float x) {
  unsigned u = __float_as_uint(x);
  return (unsigned short)((u + 0x8000u) >> 16);
}

// ---------------- attention helpers ----------------
__device__ __forceinline__ void tile_step(
    bool diag, int w, int n, int quad,
    const s8v& qf, const s8v& kf0, const s8v& kf1, const s8v& kf2, const s8v& kf3,
    const s8v& vf00, const s8v& vf01, const s8v& vf10, const s8v& vf11,
    float& lp, f4v& O0, f4v& O1) {
  const f4v zero{};
  f4v s0 = __builtin_amdgcn_mfma_f32_16x16x32_bf16(kf0, qf, zero, 0, 0, 0);
  f4v s1 = __builtin_amdgcn_mfma_f32_16x16x32_bf16(kf1, qf, zero, 0, 0, 0);
  f4v s2 = __builtin_amdgcn_mfma_f32_16x16x32_bf16(kf2, qf, zero, 0, 0, 0);
  f4v s3 = __builtin_amdgcn_mfma_f32_16x16x32_bf16(kf3, qf, zero, 0, 0, 0);
  float p[16];
#pragma unroll
  for (int r = 0; r < 4; ++r) {
    p[0 * 4 + r] = s0[r];
    p[1 * 4 + r] = s1[r];
    p[2 * 4 + r] = s2[r];
    p[3 * 4 + r] = s3[r];
  }
  if (diag) {
    int qa = w * 16 + n;
#pragma unroll
    for (int f = 0; f < 4; ++f)
#pragma unroll
      for (int r = 0; r < 4; ++r) {
        int ka = ((f >> 1) << 5) + quad * 8 + ((f & 1) << 2) + r;
        if (ka > qa) p[f * 4 + r] = -1e30f;
      }
  }
#pragma unroll
  for (int i = 0; i < 16; ++i) {
    p[i] = __builtin_amdgcn_exp2f(p[i]);   // scores pre-scaled by log2e; masked -> 0
    lp += p[i];
  }
  s8v pf0, pf1;
#pragma unroll
  for (int j = 0; j < 8; ++j) {
    pf0[j] = (short)f2bf(p[j]);
    pf1[j] = (short)f2bf(p[8 + j]);
  }
  O0 = __builtin_amdgcn_mfma_f32_16x16x32_bf16(pf0, vf00, O0, 0, 0, 0);
  O0 = __builtin_amdgcn_mfma_f32_16x16x32_bf16(pf1, vf10, O0, 0, 0, 0);
  O1 = __builtin_amdgcn_mfma_f32_16x16x32_bf16(pf0, vf01, O1, 0, 0, 0);
  O1 = __builtin_amdgcn_mfma_f32_16x16x32_bf16(pf1, vf11, O1, 0, 0, 0);
}

__device__ __forceinline__ void attn_write(
    unsigned short* __restrict__ fb, int bh, int qt, int w, int n, int quad,
    float l, const f4v& O0, const f4v& O1) {
  float linv = 1.f / l;
  const int b = bh >> 4, h = bh & 15;
#pragma unroll
  for (int r = 0; r < 4; ++r) {
    float lr = __shfl(linv, quad * 4 + r, 64);
    int qabs = qt * 64 + w * 16 + quad * 4 + r;
    int rglob = b * 2048 + qabs;
    int rt16 = rglob >> 4, m = rglob & 15;
    size_t base = (size_t)(rt16 * 16 + h) * 512;
    fb[base + ((n >> 3) * 16 + m) * 8 + (n & 7)] = f2bf(O0[r] * lr);
    fb[base + ((2 + (n >> 3)) * 16 + m) * 8 + (n & 7)] = f2bf(O1[r] * lr);
  }
}

// ================= the whole model as one cooperative kernel =================
__global__ __launch_bounds__(256, 2)
void mega_kernel(const float* __restrict__ x, const float* __restrict__ Wl,
                 const float* __restrict__ bl, const float* __restrict__ Wq,
                 const float* __restrict__ Wk, const float* __restrict__ Wv,
                 const float* __restrict__ Wo, const float* __restrict__ bo,
                 unsigned short* __restrict__ wla, unsigned short* __restrict__ wxb,
                 unsigned short* __restrict__ wbb, float* __restrict__ beff,
                 unsigned short* __restrict__ qkv, unsigned short* __restrict__ xb,
                 unsigned short* __restrict__ fb, unsigned short* __restrict__ wob,
                 float* __restrict__ out) {
  cg::grid_group grid = cg::this_grid();
  const int bid0 = blockIdx.x;   // 0..511
  const int t = threadIdx.x;
  __shared__ __align__(16) char smem[16640];   // union across phases
  float* ldsf = (float*)smem;

  // ============ Phase A: wlconv + wxconv + beff + xconv + woconv (2608 units) ============
  for (int u = bid0; u < 2608; u += 512) {
    __syncthreads();
    if (u < 1024) {
      // ---- wlconv (LDS transpose): wla[h][it16][kc][lane][j] = Wl[h][o][i] ----
      const int it64 = u & 7, ot64 = (u >> 3) & 7, h = u >> 6;
#pragma unroll
      for (int k = 0; k < 16; k++) {
        int idx = t + k * 256;
        ldsf[(idx >> 6) * 65 + (idx & 63)] =
            Wl[((size_t)(h * INn + ot64 * 64 + (idx >> 6))) * INn + it64 * 64 + (idx & 63)];
      }
      __syncthreads();
      const int itsub = t >> 6, lane = t & 63;
      const int n = lane & 15, quad = lane >> 4;
      s8v* wlav = (s8v*)wla;
#pragma unroll
      for (int kcsub = 0; kcsub < 2; kcsub++) {
        s8v v;
#pragma unroll
        for (int j = 0; j < 8; j++)
          v[j] = (short)f2bf(ldsf[(kcsub * 32 + quad * 8 + j) * 65 + itsub * 16 + n]);
        wlav[((h * 32 + it64 * 4 + itsub) * 16 + ot64 * 2 + kcsub) * 64 + lane] = v;
      }
    } else if (u < 1408) {
      // ---- wxconv: B-frags of Wq/Wk/Wv (K pre-scaled by log2e) ----
      const int v0 = u - 1024;          // 0..383
      const int nt = v0 >> 6;
      const int lane = t & 63;
      const int hk = (v0 & 63) * 4 + (t >> 6);
      const int h = hk >> 4, kc = hk & 15;
      const int which = nt >> 1;
      const float* Wx = which == 0 ? Wq : (which == 1 ? Wk : Wv);
      const float scale = (which == 1) ? LOG2E : 1.0f;
      const int dd = (nt & 1) * 16 + (lane & 15);
      const int o0 = kc * 32 + (lane >> 4) * 8;
      s8v v;
#pragma unroll
      for (int j = 0; j < 8; j++)
        v[j] = (short)f2bf(Wx[((size_t)(h * INn + o0 + j)) * HDn + dd] * scale);
      ((s8v*)wxb)[((h * 16 + kc) * 6 + nt) * 64 + lane] = v;
    } else if (u < 1456) {
      // ---- beff ----
      const int v0 = u - 1408;          // 0..47
      const int h = v0 & 15, which = v0 >> 4;
      const float* Wx = which == 0 ? Wq : (which == 1 ? Wk : Wv);
      const float scale = (which == 1) ? LOG2E : 1.0f;
      const int d = t & 31, oc = t >> 5;
      float p = 0.f;
      for (int k = 0; k < 64; k++) {
        int o = oc * 64 + k;
        p += bl[h * INn + o] * Wx[(h * INn + o) * HDn + d];
      }
      ldsf[t] = p;
      __syncthreads();
      if (t < 32) {
        float s = 0.f;
#pragma unroll
        for (int k = 0; k < 8; k++) s += ldsf[t + 32 * k];
        beff[which * (Hn * HDn) + h * HDn + t] = s * scale;
      }
    } else if (u < 2480) {
      // ---- xconv: x -> A-frags ----
      const int tid = (u - 1456) * 256 + t;
      const int lane = tid & 63;
      const int rk = tid >> 6;
      const int rt16 = rk >> 4, kc = rk & 15;
      const float* src = x + (size_t)(rt16 * 16 + (lane & 15)) * INn + kc * 32 + (lane >> 4) * 8;
      unsigned short* dst = xb + (size_t)tid * 8;
#pragma unroll
      for (int j = 0; j < 8; j++) dst[j] = f2bf(src[j]);
    } else {
      // ---- woconv: Wo -> B-frags ----
      const int tid = (u - 2480) * 256 + t;
      const int lane = tid & 63;
      const int kn = tid >> 6;
      const int kc = kn >> 5, nt = kn & 31;
      const float* src = Wo + (size_t)(nt * 16 + (lane & 15)) * INn + kc * 32 + (lane >> 4) * 8;
      unsigned short* dst = wob + (size_t)tid * 8;
#pragma unroll
      for (int j = 0; j < 8; j++) dst[j] = f2bf(src[j]);
    }
  }
  grid.sync();

  // ============ Phase B: Weff MFMA -> B-frags (256 units) ============
  if (bid0 < 256) {
    unsigned short* clds = (unsigned short*)smem;   // 32*97 ushort
    const int bx = bid0 & 15, h = bid0 >> 4;
    const int lane = t & 63, w = t >> 6;
    const int n = lane & 15, quad = lane >> 4;
    const int it16 = bx * 2 + (w & 1);
    const int nt0 = (w >> 1) * 3;
    const s8v* wlav = (const s8v*)wla;
    const s8v* wxbv = (const s8v*)wxb;
    f4v acc[3] = {};
#pragma unroll 4
    for (int kc = 0; kc < 16; ++kc) {
      s8v a = wlav[((h * 32 + it16) * 16 + kc) * 64 + lane];
      const s8v* wp = wxbv + (size_t)((h * 16 + kc) * 6 + nt0) * 64 + lane;
#pragma unroll
      for (int q = 0; q < 3; ++q)
        acc[q] = __builtin_amdgcn_mfma_f32_16x16x32_bf16(a, wp[q * 64], acc[q], 0, 0, 0);
    }
#pragma unroll
    for (int q = 0; q < 3; ++q)
#pragma unroll
      for (int reg = 0; reg < 4; ++reg) {
        int i_local = (w & 1) * 16 + quad * 4 + reg;
        int n96 = (nt0 + q) * 16 + n;
        clds[i_local * 97 + n96] = f2bf(acc[q][reg]);
      }
    __syncthreads();
    s8v* wbbv = (s8v*)wbb;
    for (int nt = w; nt < 6; nt += 4) {
      s8v v;
#pragma unroll
      for (int j = 0; j < 8; j++)
        v[j] = (short)clds[((lane >> 4) * 8 + j) * 97 + nt * 16 + (lane & 15)];
      wbbv[((h * 16 + bx) * 6 + nt) * 64 + lane] = v;
    }
  }
  grid.sync();

  // ============ Phase C: QKV projection (1024 units) ============
  for (int u = bid0; u < 1024; u += 512) {
    __syncthreads();
    const int rt64 = u & 63, h = u >> 6;
    const int lane = t & 63, w = t >> 6;
    const int n = lane & 15, quad = lane >> 4;
    const s8v* xbv = (const s8v*)xb;
    const s8v* wbbv = (const s8v*)wbb;
    const int rt16 = rt64 * 4 + w;
    f4v acc[6] = {};
#pragma unroll 4
    for (int kc = 0; kc < 16; ++kc) {
      s8v a = xbv[(rt16 * 16 + kc) * 64 + lane];
      const s8v* wp = wbbv + (size_t)((h * 16 + kc) * 6) * 64 + lane;
#pragma unroll
      for (int nt = 0; nt < 6; ++nt)
        acc[nt] = __builtin_amdgcn_mfma_f32_16x16x32_bf16(a, wp[nt * 64], acc[nt], 0, 0, 0);
    }
    unsigned short* eld = (unsigned short*)smem;    // 3*2048 ushort
#pragma unroll
    for (int nt = 0; nt < 6; ++nt) {
      const int which = nt >> 1;
      const int dd = (nt & 1) * 16 + n;
      const float bias = beff[which * 512 + h * 32 + dd];
#pragma unroll
      for (int reg = 0; reg < 4; ++reg) {
        const int kl = w * 16 + quad * 4 + reg;
        unsigned short val = f2bf(acc[nt][reg] + bias);
        int off;
        if (which == 0) {
          off = (((kl >> 4) * 4 + (dd >> 3)) * 16 + (kl & 15)) * 8 + (dd & 7);
        } else if (which == 1) {
          int f = ((kl >> 5) << 1) | ((kl >> 2) & 1);
          int mm = ((kl >> 3) & 3) * 4 + (kl & 3);
          off = ((f * 4 + (dd >> 3)) * 16 + mm) * 8 + (dd & 7);
        } else {
          off = ((((kl >> 5) * 2 + (dd >> 4)) * 4 + ((kl >> 3) & 3)) * 16 + (dd & 15)) * 8 + (kl & 7);
        }
        eld[which * 2048 + off] = val;
      }
    }
    __syncthreads();
    const int b = rt64 >> 5;
    const int ts = rt64 & 31;
    const size_t tilebase = ((size_t)((b * Hn + h) * 32) + ts) * 2048;
    const s8v* eldv = (const s8v*)eld;
#pragma unroll
    for (int c = 0; c < 3; ++c) {
      int idx = c * 256 + t;
      int which = idx >> 8, k8 = idx & 255;
      *((s8v*)(qkv + (size_t)which * NQ + tilebase) + k8) = eldv[idx];
    }
  }
  grid.sync();

  // ============ Phase D: flash attention (512 paired units) ============
  {
    const int qp = bid0 & 15, bh = bid0 >> 4;
    const int qtA = qp, qtB = 31 - qp;
    const int lane = t & 63, w = t >> 6;
    const int n = lane & 15, quad = lane >> 4;
    s8v* q_sh = (s8v*)smem;          // 512
    s8v* k_sh = q_sh + 512;          // 256
    s8v* v_sh = k_sh + 256;          // 256 -> 16384 B total
    const s8v* Qs = (const s8v*)qkv + (size_t)bh * 32 * 256;
    const s8v* Ks = (const s8v*)(qkv + NQ) + (size_t)bh * 32 * 256;
    const s8v* Vs = (const s8v*)(qkv + 2 * NQ) + (size_t)bh * 32 * 256;
    q_sh[t] = Qs[qtA * 256 + t];
    q_sh[256 + t] = Qs[qtB * 256 + t];
    s8v kpre = Ks[t];
    s8v vpre = Vs[t];
    __syncthreads();
    s8v qfA = q_sh[w * 64 + lane];
    s8v qfB = q_sh[256 + w * 64 + lane];
    f4v OA0{}, OA1{}, OB0{}, OB1{};
    float lpA = 0.f, lpB = 0.f;
    for (int kt = 0; kt <= qtB; ++kt) {
      __syncthreads();
      k_sh[t] = kpre;
      v_sh[t] = vpre;
      __syncthreads();
      if (kt < qtB) {
        kpre = Ks[(kt + 1) * 256 + t];
        vpre = Vs[(kt + 1) * 256 + t];
      }
      s8v kf0 = k_sh[lane], kf1 = k_sh[64 + lane], kf2 = k_sh[128 + lane], kf3 = k_sh[192 + lane];
      s8v vf00 = v_sh[lane], vf01 = v_sh[64 + lane], vf10 = v_sh[128 + lane], vf11 = v_sh[192 + lane];
      if (kt <= qtA)
        tile_step(kt == qtA, w, n, quad, qfA, kf0, kf1, kf2, kf3,
                  vf00, vf01, vf10, vf11, lpA, OA0, OA1);
      tile_step(kt == qtB, w, n, quad, qfB, kf0, kf1, kf2, kf3,
                vf00, vf01, vf10, vf11, lpB, OB0, OB1);
    }
    lpA += __shfl_xor(lpA, 16); lpA += __shfl_xor(lpA, 32);
    lpB += __shfl_xor(lpB, 16); lpB += __shfl_xor(lpB, 32);
    attn_write(fb, bh, qtA, w, n, quad, lpA, OA0, OA1);
    attn_write(fb, bh, qtB, w, n, quad, lpB, OB0, OB1);
  }
  grid.sync();

  // ============ Phase E: output projection (512 units, 64x64 tiles) ============
  {
    const int rt64 = bid0 >> 3, jt = bid0 & 7;
    const int lane = t & 63, w = t >> 6;
    const int n = lane & 15, quad = lane >> 4;
    const s8v* fbv = (const s8v*)fb;
    const s8v* wobv = (const s8v*)wob;
    const int rt16 = rt64 * 4 + w;
    f4v acc[4] = {};
#pragma unroll 4
    for (int kc = 0; kc < 16; ++kc) {
      s8v a = fbv[(rt16 * 16 + kc) * 64 + lane];
      const s8v* wp = wobv + (size_t)(kc * 32 + jt * 4) * 64 + lane;
#pragma unroll
      for (int i = 0; i < 4; ++i)
        acc[i] = __builtin_amdgcn_mfma_f32_16x16x32_bf16(a, wp[i * 64], acc[i], 0, 0, 0);
    }
#pragma unroll
    for (int i = 0; i < 4; ++i) {
      const int j = jt * 64 + i * 16 + n;
      const float bias = bo[j];
#pragma unroll
      for (int reg = 0; reg < 4; ++reg) {
        int r = rt64 * 64 + w * 16 + quad * 4 + reg;
        out[(size_t)r * INn + j] = acc[i][reg] + bias;
      }
    }
  }
}

extern "C" void kernel_launch(void* const* d_in, const int* in_sizes, int n_in,
                              void* d_out, int out_size, void* d_ws, size_t ws_size,
                              hipStream_t stream) {
  const float* x  = (const float*)d_in[0];
  const float* Wl = (const float*)d_in[1];
  const float* bl = (const float*)d_in[2];
  const float* Wq = (const float*)d_in[3];
  const float* Wk = (const float*)d_in[4];
  const float* Wv = (const float*)d_in[5];
  const float* Wo = (const float*)d_in[6];
  const float* bo = (const float*)d_in[7];
  float* ws = (float*)d_ws;
  float* out = (float*)d_out;
  unsigned short* wla = (unsigned short*)(ws + OFF_WLA);
  unsigned short* wxb = (unsigned short*)(ws + OFF_WXB);
  unsigned short* wbb = (unsigned short*)(ws + OFF_WBB);
  float*          beff = ws + OFF_BEFF;
  unsigned short* qkv = (unsigned short*)(ws + OFF_QKV);
  unsigned short* xb  = (unsigned short*)(ws + OFF_XB);
  unsigned short* fb  = (unsigned short*)(ws + OFF_FB);
  unsigned short* wob = (unsigned short*)(ws + OFF_WOB);

  void* args[] = {
    (void*)&x, (void*)&Wl, (void*)&bl, (void*)&Wq, (void*)&Wk, (void*)&Wv,
    (void*)&Wo, (void*)&bo, (void*)&wla, (void*)&wxb, (void*)&wbb, (void*)&beff,
    (void*)&qkv, (void*)&xb, (void*)&fb, (void*)&wob, (void*)&out
  };
  (void)hipLaunchCooperativeKernel((void*)mega_kernel, dim3(512), dim3(256), args, 0, stream);
}

// Round 8
// 209.628 us; speedup vs baseline: 1.9494x; 1.9494x over previous
//
#include <hip/hip_runtime.h>
#include <math.h>

namespace {
constexpr int Bn = 2, Sn = 2048, INn = 512, HDn = 32, Hn = 16;
constexpr int NQ = Bn * Hn * Sn * HDn;           // 2097152 bf16 elems per K/V tensor
// ws offsets in FLOAT units — all regions DISJOINT
constexpr int OFF_WLA = 0;          // Wl A-frags bf16: 4194304 bf16 -> 2097152 fl
constexpr int OFF_WXB = 2097152;    // Wq/k/v B-frags bf16: 786432 bf16 -> 393216 fl
constexpr int OFF_WBB = 2490368;    // Weff B-frags bf16: 786432 bf16 -> 393216 fl
constexpr int OFF_BEFF = 2883584;   // 1536 fl
constexpr int OFF_KV = 2885120;     // K,V swizzled bf16: 2*2097152 -> 2097152 fl
constexpr int OFF_CNT = 4982272;    // 32 uint barrier counters
constexpr int OFF_XB = 6030848;     // x A-frags bf16 -> 1048576 fl
constexpr int OFF_FB = 7079424;     // F A-frags bf16 -> 1048576 fl
constexpr int OFF_WOB = 8128000;    // Wo B-frags bf16 -> 131072 fl
constexpr float LOG2E = 1.44269504f;
}

typedef __attribute__((ext_vector_type(8))) short s8v;   // 8 bf16 in 4 VGPRs
typedef __attribute__((ext_vector_type(4))) float f4v;   // MFMA accumulator

__device__ __forceinline__ unsigned short f2bf(float x) {
  unsigned u = __float_as_uint(x);
  return (unsigned short)((u + 0x8000u) >> 16);
}

// ================= prep: wlconv + wxconv + beff (flat grid 1456) =================
__global__ __launch_bounds__(256)
void prep_kernel(const float* __restrict__ Wl, const float* __restrict__ bl,
                 const float* __restrict__ Wq, const float* __restrict__ Wk,
                 const float* __restrict__ Wv,
                 unsigned short* __restrict__ wla, unsigned short* __restrict__ wxb,
                 float* __restrict__ beff) {
  const int bid = blockIdx.x;
  const int t = threadIdx.x;
  __shared__ float lds[64 * 65];
  if (bid < 1024) {
    // ---- wlconv (LDS transpose): wla[h][it16][kc][lane][j] = Wl[h][o][i] ----
    const int it64 = bid & 7, ot64 = (bid >> 3) & 7, h = bid >> 6;
#pragma unroll
    for (int k = 0; k < 16; k++) {
      int idx = t + k * 256;
      lds[(idx >> 6) * 65 + (idx & 63)] =
          Wl[((size_t)(h * INn + ot64 * 64 + (idx >> 6))) * INn + it64 * 64 + (idx & 63)];
    }
    __syncthreads();
    const int itsub = t >> 6, lane = t & 63;
    const int n = lane & 15, quad = lane >> 4;
    s8v* wlav = (s8v*)wla;
#pragma unroll
    for (int kcsub = 0; kcsub < 2; kcsub++) {
      s8v v;
#pragma unroll
      for (int j = 0; j < 8; j++)
        v[j] = (short)f2bf(lds[(kcsub * 32 + quad * 8 + j) * 65 + itsub * 16 + n]);
      wlav[((h * 32 + it64 * 4 + itsub) * 16 + ot64 * 2 + kcsub) * 64 + lane] = v;
    }
  } else if (bid < 1408) {
    // ---- wxconv: B-frags of Wq/Wk/Wv (K pre-scaled by log2e) ----
    const int v0 = bid - 1024;        // 0..383
    const int nt = v0 >> 6;
    const int lane = t & 63;
    const int hk = (v0 & 63) * 4 + (t >> 6);
    const int h = hk >> 4, kc = hk & 15;
    const int which = nt >> 1;
    const float* Wx = which == 0 ? Wq : (which == 1 ? Wk : Wv);
    const float scale = (which == 1) ? LOG2E : 1.0f;
    const int dd = (nt & 1) * 16 + (lane & 15);
    const int o0 = kc * 32 + (lane >> 4) * 8;
    s8v v;
#pragma unroll
    for (int j = 0; j < 8; j++)
      v[j] = (short)f2bf(Wx[((size_t)(h * INn + o0 + j)) * HDn + dd] * scale);
    ((s8v*)wxb)[((h * 16 + kc) * 6 + nt) * 64 + lane] = v;
  } else {
    // ---- beff ----
    const int v0 = bid - 1408;        // 0..47
    const int h = v0 & 15, which = v0 >> 4;
    const float* Wx = which == 0 ? Wq : (which == 1 ? Wk : Wv);
    const float scale = (which == 1) ? LOG2E : 1.0f;
    const int d = t & 31, oc = t >> 5;
    float p = 0.f;
    for (int k = 0; k < 64; k++) {
      int o = oc * 64 + k;
      p += bl[h * INn + o] * Wx[(h * INn + o) * HDn + d];
    }
    lds[t] = p;
    __syncthreads();
    if (t < 32) {
      float s = 0.f;
#pragma unroll
      for (int k = 0; k < 8; k++) s += lds[t + 32 * k];
      beff[which * (Hn * HDn) + h * HDn + t] = s * scale;
    }
  }
}

// ========== midphase: weff MFMA + xconv + woconv + barrier-counter zero (1408) ==========
__global__ __launch_bounds__(256)
void midphase_kernel(const unsigned short* __restrict__ wla_u,
                     const unsigned short* __restrict__ wxb_u,
                     unsigned short* __restrict__ wbb,
                     const float* __restrict__ x, unsigned short* __restrict__ xb,
                     const float* __restrict__ Wo, unsigned short* __restrict__ wob,
                     unsigned int* __restrict__ cnt) {
  const int bid = blockIdx.x;
  const int t = threadIdx.x;
  __shared__ unsigned short clds[32 * 97];
  if (bid < 256) {
    const int bx = bid & 15, h = bid >> 4;
    const int lane = t & 63, w = t >> 6;
    const int n = lane & 15, quad = lane >> 4;
    const int it16 = bx * 2 + (w & 1);
    const int nt0 = (w >> 1) * 3;
    const s8v* wlav = (const s8v*)wla_u;
    const s8v* wxbv = (const s8v*)wxb_u;
    f4v acc[3] = {};
#pragma unroll 4
    for (int kc = 0; kc < 16; ++kc) {
      s8v a = wlav[((h * 32 + it16) * 16 + kc) * 64 + lane];
      const s8v* wp = wxbv + (size_t)((h * 16 + kc) * 6 + nt0) * 64 + lane;
#pragma unroll
      for (int q = 0; q < 3; ++q)
        acc[q] = __builtin_amdgcn_mfma_f32_16x16x32_bf16(a, wp[q * 64], acc[q], 0, 0, 0);
    }
#pragma unroll
    for (int q = 0; q < 3; ++q)
#pragma unroll
      for (int reg = 0; reg < 4; ++reg) {
        int i_local = (w & 1) * 16 + quad * 4 + reg;
        int n96 = (nt0 + q) * 16 + n;
        clds[i_local * 97 + n96] = f2bf(acc[q][reg]);
      }
    __syncthreads();
    s8v* wbbv = (s8v*)wbb;
    for (int nt = w; nt < 6; nt += 4) {
      s8v v;
#pragma unroll
      for (int j = 0; j < 8; j++)
        v[j] = (short)clds[((lane >> 4) * 8 + j) * 97 + nt * 16 + (lane & 15)];
      wbbv[((h * 16 + bx) * 6 + nt) * 64 + lane] = v;
    }
  } else if (bid < 1280) {
    // ---- xconv ----
    const int tid = (bid - 256) * 256 + t;
    const int lane = tid & 63;
    const int rk = tid >> 6;
    const int rt16 = rk >> 4, kc = rk & 15;
    const float* src = x + (size_t)(rt16 * 16 + (lane & 15)) * INn + kc * 32 + (lane >> 4) * 8;
    unsigned short* dst = xb + (size_t)tid * 8;
#pragma unroll
    for (int j = 0; j < 8; j++) dst[j] = f2bf(src[j]);
  } else {
    // ---- woconv (+ zero group-barrier counters) ----
    if (bid == 1280 && t < 32) cnt[t] = 0;
    const int tid = (bid - 1280) * 256 + t;
    const int lane = tid & 63;
    const int kn = tid >> 6;
    const int kc = kn >> 5, nt = kn & 31;
    const float* src = Wo + (size_t)(nt * 16 + (lane & 15)) * INn + kc * 32 + (lane >> 4) * 8;
    unsigned short* dst = wob + (size_t)tid * 8;
#pragma unroll
    for (int j = 0; j < 8; j++) dst[j] = f2bf(src[j]);
  }
}

// ---------------- fused qkv+attn helpers ----------------
__device__ __forceinline__ void qkv_epilogue(
    const f4v (&acc)[6], int qslot, int qt, int bh, int h,
    int w, int n, int quad, int t,
    const float* __restrict__ beff, unsigned short* q_sh,
    unsigned short* scratch, unsigned short* __restrict__ kv) {
#pragma unroll
  for (int nt = 0; nt < 6; ++nt) {
    const int which = nt >> 1;
    const int dd = (nt & 1) * 16 + n;
    const float bias = beff[which * 512 + h * 32 + dd];
#pragma unroll
    for (int reg = 0; reg < 4; ++reg) {
      const int kl = w * 16 + quad * 4 + reg;
      unsigned short val = f2bf(acc[nt][reg] + bias);
      if (which == 0) {
        int off = (((kl >> 4) * 4 + (dd >> 3)) * 16 + (kl & 15)) * 8 + (dd & 7);
        q_sh[qslot * 2048 + off] = val;          // Q stays in LDS
      } else if (which == 1) {
        int f = ((kl >> 5) << 1) | ((kl >> 2) & 1);
        int mm = ((kl >> 3) & 3) * 4 + (kl & 3);
        int off = ((f * 4 + (dd >> 3)) * 16 + mm) * 8 + (dd & 7);
        scratch[off] = val;
      } else {
        int off = ((((kl >> 5) * 2 + (dd >> 4)) * 4 + ((kl >> 3) & 3)) * 16 + (dd & 15)) * 8 + (kl & 7);
        scratch[2048 + off] = val;
      }
    }
  }
  __syncthreads();
  const size_t tilebase = ((size_t)bh * 32 + qt) * 2048;
  s8v* Kd = (s8v*)(kv + tilebase);
  s8v* Vd = (s8v*)(kv + (size_t)NQ + tilebase);
  const s8v* sv = (const s8v*)scratch;
  Kd[t] = sv[t];
  Vd[t] = sv[256 + t];
}

__device__ __forceinline__ void tile_step(
    bool diag, int w, int n, int quad,
    const s8v& qf, const s8v& kf0, const s8v& kf1, const s8v& kf2, const s8v& kf3,
    const s8v& vf00, const s8v& vf01, const s8v& vf10, const s8v& vf11,
    float& lp, f4v& O0, f4v& O1) {
  const f4v zero{};
  f4v s0 = __builtin_amdgcn_mfma_f32_16x16x32_bf16(kf0, qf, zero, 0, 0, 0);
  f4v s1 = __builtin_amdgcn_mfma_f32_16x16x32_bf16(kf1, qf, zero, 0, 0, 0);
  f4v s2 = __builtin_amdgcn_mfma_f32_16x16x32_bf16(kf2, qf, zero, 0, 0, 0);
  f4v s3 = __builtin_amdgcn_mfma_f32_16x16x32_bf16(kf3, qf, zero, 0, 0, 0);
  float p[16];
#pragma unroll
  for (int r = 0; r < 4; ++r) {
    p[0 * 4 + r] = s0[r];
    p[1 * 4 + r] = s1[r];
    p[2 * 4 + r] = s2[r];
    p[3 * 4 + r] = s3[r];
  }
  if (diag) {
    int qa = w * 16 + n;
#pragma unroll
    for (int f = 0; f < 4; ++f)
#pragma unroll
      for (int r = 0; r < 4; ++r) {
        int ka = ((f >> 1) << 5) + quad * 8 + ((f & 1) << 2) + r;
        if (ka > qa) p[f * 4 + r] = -1e30f;
      }
  }
#pragma unroll
  for (int i = 0; i < 16; ++i) {
    p[i] = __builtin_amdgcn_exp2f(p[i]);   // scores pre-scaled by log2e; masked -> 0
    lp += p[i];
  }
  s8v pf0, pf1;
#pragma unroll
  for (int j = 0; j < 8; ++j) {
    pf0[j] = (short)f2bf(p[j]);
    pf1[j] = (short)f2bf(p[8 + j]);
  }
  O0 = __builtin_amdgcn_mfma_f32_16x16x32_bf16(pf0, vf00, O0, 0, 0, 0);
  O0 = __builtin_amdgcn_mfma_f32_16x16x32_bf16(pf1, vf10, O0, 0, 0, 0);
  O1 = __builtin_amdgcn_mfma_f32_16x16x32_bf16(pf0, vf01, O1, 0, 0, 0);
  O1 = __builtin_amdgcn_mfma_f32_16x16x32_bf16(pf1, vf11, O1, 0, 0, 0);
}

__device__ __forceinline__ void attn_write(
    unsigned short* __restrict__ fb, int bh, int qt, int w, int n, int quad,
    float l, const f4v& O0, const f4v& O1) {
  float linv = 1.f / l;
  const int b = bh >> 4, h = bh & 15;
#pragma unroll
  for (int r = 0; r < 4; ++r) {
    float lr = __shfl(linv, quad * 4 + r, 64);
    int qabs = qt * 64 + w * 16 + quad * 4 + r;
    int rglob = b * 2048 + qabs;
    int rt16 = rglob >> 4, m = rglob & 15;
    size_t base = (size_t)(rt16 * 16 + h) * 512;
    fb[base + ((n >> 3) * 16 + m) * 8 + (n & 7)] = f2bf(O0[r] * lr);
    fb[base + ((2 + (n >> 3)) * 16 + m) * 8 + (n & 7)] = f2bf(O1[r] * lr);
  }
}

// ================= fused QKV + flash attention (per-(b,h) group barrier) =================
// grid (16, 32): x = q-tile pair (qp, 31-qp), y = bh. 16 blocks per bh group.
// All 512 blocks co-resident (24 KB LDS, <=256 VGPR at 2 blocks/CU) -> spin is safe.
__global__ __launch_bounds__(256, 2)
void qkv_attn_kernel(const unsigned short* __restrict__ xb_u,
                     const unsigned short* __restrict__ wbb_u,
                     const float* __restrict__ beff,
                     unsigned short* __restrict__ kv,
                     unsigned int* __restrict__ cnt,
                     unsigned short* __restrict__ fb) {
  const int qp = blockIdx.x, bh = blockIdx.y;
  const int qtA = qp, qtB = 31 - qp;
  const int b = bh >> 4, h = bh & 15;
  const int t = threadIdx.x;
  const int lane = t & 63, w = t >> 6;
  const int n = lane & 15, quad = lane >> 4;
  __shared__ __align__(16) unsigned short q_sh[2 * 2048];   // Q tiles A,B (never to global)
  __shared__ __align__(16) unsigned short scratch[8192];    // phase1: K/V eld; phase2: k/v dbuf

  // ---- phase 1: project both q-tiles in one pass over the B operand ----
  {
    const s8v* xbv = (const s8v*)xb_u;
    const s8v* wbbv = (const s8v*)wbb_u;
    const int rtA = (b * 32 + qtA) * 4 + w;
    const int rtB = (b * 32 + qtB) * 4 + w;
    f4v accA[6] = {}, accB[6] = {};
#pragma unroll 2
    for (int kc = 0; kc < 16; ++kc) {
      s8v aA = xbv[(rtA * 16 + kc) * 64 + lane];
      s8v aB = xbv[(rtB * 16 + kc) * 64 + lane];
      const s8v* wp = wbbv + (size_t)((h * 16 + kc) * 6) * 64 + lane;
#pragma unroll
      for (int nt = 0; nt < 6; ++nt) {
        s8v bb = wp[nt * 64];
        accA[nt] = __builtin_amdgcn_mfma_f32_16x16x32_bf16(aA, bb, accA[nt], 0, 0, 0);
        accB[nt] = __builtin_amdgcn_mfma_f32_16x16x32_bf16(aB, bb, accB[nt], 0, 0, 0);
      }
    }
    qkv_epilogue(accA, 0, qtA, bh, h, w, n, quad, t, beff, q_sh, scratch, kv);
    __syncthreads();   // eld reads done before reuse
    qkv_epilogue(accB, 1, qtB, bh, h, w, n, quad, t, beff, q_sh, scratch, kv);
  }

  // ---- group barrier: release K/V, wait for all 16 producer blocks of this bh ----
  __syncthreads();                       // drains vmcnt for all threads' stores
  if (t == 0) {
    __threadfence();                     // release (wbl2)
    atomicAdd(cnt + bh, 1u);
    int guard = 0;
    while (atomicAdd(cnt + bh, 0u) < 16u && guard < (1 << 22)) {
      __builtin_amdgcn_s_sleep(2);
      ++guard;
    }
  }
  __syncthreads();
  __threadfence();                       // acquire (invalidate caches)

  // ---- phase 2: flash attention, double-buffered K/V, one barrier per tile ----
  {
    const s8v* Ks = (const s8v*)kv + (size_t)bh * 32 * 256;
    const s8v* Vs = (const s8v*)(kv + (size_t)NQ) + (size_t)bh * 32 * 256;
    s8v* kvbuf = (s8v*)scratch;          // [2][k:256 | v:256]
    const s8v* qshv = (const s8v*)q_sh;
    s8v qfA = qshv[w * 64 + lane];
    s8v qfB = qshv[256 + w * 64 + lane];
    f4v OA0{}, OA1{}, OB0{}, OB1{};
    float lpA = 0.f, lpB = 0.f;
    s8v kpre = Ks[t];
    s8v vpre = Vs[t];
    for (int kt = 0; kt <= qtB; ++kt) {
      const int c = kt & 1;
      kvbuf[c * 512 + t] = kpre;
      kvbuf[c * 512 + 256 + t] = vpre;
      __syncthreads();
      if (kt < qtB) {
        kpre = Ks[(kt + 1) * 256 + t];
        vpre = Vs[(kt + 1) * 256 + t];
      }
      const s8v* kb = kvbuf + c * 512;
      const s8v* vb = kb + 256;
      s8v kf0 = kb[lane], kf1 = kb[64 + lane], kf2 = kb[128 + lane], kf3 = kb[192 + lane];
      s8v vf00 = vb[lane], vf01 = vb[64 + lane], vf10 = vb[128 + lane], vf11 = vb[192 + lane];
      if (kt <= qtA)
        tile_step(kt == qtA, w, n, quad, qfA, kf0, kf1, kf2, kf3,
                  vf00, vf01, vf10, vf11, lpA, OA0, OA1);
      tile_step(kt == qtB, w, n, quad, qfB, kf0, kf1, kf2, kf3,
                vf00, vf01, vf10, vf11, lpB, OB0, OB1);
    }
    lpA += __shfl_xor(lpA, 16); lpA += __shfl_xor(lpA, 32);
    lpB += __shfl_xor(lpB, 16); lpB += __shfl_xor(lpB, 32);
    attn_write(fb, bh, qtA, w, n, quad, lpA, OA0, OA1);
    attn_write(fb, bh, qtB, w, n, quad, lpB, OB0, OB1);
  }
}

// ================= output projection: zero-LDS MFMA GEMM =================
__global__ __launch_bounds__(256)
void outproj_mfma_kernel(const unsigned short* __restrict__ fb_u,
                         const unsigned short* __restrict__ wob_u,
                         const float* __restrict__ bo,
                         float* __restrict__ out) {
  const int rt64 = blockIdx.x;  // 64
  const int jt = blockIdx.y;    // 4
  const int t = threadIdx.x;
  const int lane = t & 63, w = t >> 6;
  const int n = lane & 15, quad = lane >> 4;
  const s8v* fbv = (const s8v*)fb_u;
  const s8v* wobv = (const s8v*)wob_u;
  const int rt16 = rt64 * 4 + w;
  f4v acc[8] = {};
#pragma unroll 2
  for (int kc = 0; kc < 16; ++kc) {
    s8v a = fbv[(rt16 * 16 + kc) * 64 + lane];
    const s8v* wp = wobv + (size_t)(kc * 32 + jt * 8) * 64 + lane;
#pragma unroll
    for (int i = 0; i < 8; ++i)
      acc[i] = __builtin_amdgcn_mfma_f32_16x16x32_bf16(a, wp[i * 64], acc[i], 0, 0, 0);
  }
#pragma unroll
  for (int i = 0; i < 8; ++i) {
    const int j = jt * 128 + i * 16 + n;
    const float bias = bo[j];
#pragma unroll
    for (int reg = 0; reg < 4; ++reg) {
      int r = rt64 * 64 + w * 16 + quad * 4 + reg;
      out[(size_t)r * INn + j] = acc[i][reg] + bias;
    }
  }
}

extern "C" void kernel_launch(void* const* d_in, const int* in_sizes, int n_in,
                              void* d_out, int out_size, void* d_ws, size_t ws_size,
                              hipStream_t stream) {
  const float* x  = (const float*)d_in[0];
  const float* Wl = (const float*)d_in[1];
  const float* bl = (const float*)d_in[2];
  const float* Wq = (const float*)d_in[3];
  const float* Wk = (const float*)d_in[4];
  const float* Wv = (const float*)d_in[5];
  const float* Wo = (const float*)d_in[6];
  const float* bo = (const float*)d_in[7];
  float* ws = (float*)d_ws;
  float* out = (float*)d_out;
  unsigned short* wla = (unsigned short*)(ws + OFF_WLA);
  unsigned short* wxb = (unsigned short*)(ws + OFF_WXB);
  unsigned short* wbb = (unsigned short*)(ws + OFF_WBB);
  float*          beff = ws + OFF_BEFF;
  unsigned short* kv  = (unsigned short*)(ws + OFF_KV);
  unsigned int*   cnt = (unsigned int*)(ws + OFF_CNT);
  unsigned short* xb  = (unsigned short*)(ws + OFF_XB);
  unsigned short* fb  = (unsigned short*)(ws + OFF_FB);
  unsigned short* wob = (unsigned short*)(ws + OFF_WOB);

  prep_kernel<<<dim3(1456), 256, 0, stream>>>(Wl, bl, Wq, Wk, Wv, wla, wxb, beff);
  midphase_kernel<<<dim3(1408), 256, 0, stream>>>(wla, wxb, wbb, x, xb, Wo, wob, cnt);
  qkv_attn_kernel<<<dim3(16, 32), 256, 0, stream>>>(xb, wbb, beff, kv, cnt, fb);
  outproj_mfma_kernel<<<dim3(64, 4), 256, 0, stream>>>(fb, wob, bo, out);
}

// Round 9
// 200.094 us; speedup vs baseline: 2.0423x; 1.0476x over previous
//
#include <hip/hip_runtime.h>
#include <math.h>

namespace {
constexpr int Bn = 2, Sn = 2048, INn = 512, HDn = 32, Hn = 16;
constexpr int NQ = Bn * Hn * Sn * HDn;           // 2097152 bf16 elems per K/V tensor
// ws offsets in FLOAT units — all regions DISJOINT
constexpr int OFF_WLA = 0;          // Wl A-frags bf16: 4194304 bf16 -> 2097152 fl
constexpr int OFF_WXB = 2097152;    // Wq/k/v B-frags bf16: 786432 bf16 -> 393216 fl
constexpr int OFF_WBB = 2490368;    // Weff B-frags bf16: 786432 bf16 -> 393216 fl
constexpr int OFF_BEFF = 2883584;   // 1536 fl
constexpr int OFF_KV = 2885120;     // K,V swizzled bf16: 2*2097152 -> 2097152 fl
constexpr int OFF_CNT = 4982272;    // 32 barrier counters, 128B apart (1024 uints)
constexpr int OFF_XB = 6030848;     // x A-frags bf16 -> 1048576 fl
constexpr int OFF_FB = 7079424;     // F A-frags bf16 -> 1048576 fl
constexpr int OFF_WOB = 8128000;    // Wo B-frags bf16 -> 131072 fl
constexpr int CNT_STRIDE = 32;      // dwords: one counter per 128-byte line
constexpr float LOG2E = 1.44269504f;
}

typedef __attribute__((ext_vector_type(8))) short s8v;   // 8 bf16 in 4 VGPRs
typedef __attribute__((ext_vector_type(4))) float f4v;   // MFMA accumulator

__device__ __forceinline__ unsigned short f2bf(float x) {
  unsigned u = __float_as_uint(x);
  return (unsigned short)((u + 0x8000u) >> 16);
}

// ================= prep: wlconv + wxconv + beff (flat grid 1456) =================
__global__ __launch_bounds__(256)
void prep_kernel(const float* __restrict__ Wl, const float* __restrict__ bl,
                 const float* __restrict__ Wq, const float* __restrict__ Wk,
                 const float* __restrict__ Wv,
                 unsigned short* __restrict__ wla, unsigned short* __restrict__ wxb,
                 float* __restrict__ beff) {
  const int bid = blockIdx.x;
  const int t = threadIdx.x;
  __shared__ float lds[64 * 65];
  if (bid < 1024) {
    // ---- wlconv (LDS transpose): wla[h][it16][kc][lane][j] = Wl[h][o][i] ----
    const int it64 = bid & 7, ot64 = (bid >> 3) & 7, h = bid >> 6;
#pragma unroll
    for (int k = 0; k < 16; k++) {
      int idx = t + k * 256;
      lds[(idx >> 6) * 65 + (idx & 63)] =
          Wl[((size_t)(h * INn + ot64 * 64 + (idx >> 6))) * INn + it64 * 64 + (idx & 63)];
    }
    __syncthreads();
    const int itsub = t >> 6, lane = t & 63;
    const int n = lane & 15, quad = lane >> 4;
    s8v* wlav = (s8v*)wla;
#pragma unroll
    for (int kcsub = 0; kcsub < 2; kcsub++) {
      s8v v;
#pragma unroll
      for (int j = 0; j < 8; j++)
        v[j] = (short)f2bf(lds[(kcsub * 32 + quad * 8 + j) * 65 + itsub * 16 + n]);
      wlav[((h * 32 + it64 * 4 + itsub) * 16 + ot64 * 2 + kcsub) * 64 + lane] = v;
    }
  } else if (bid < 1408) {
    // ---- wxconv: B-frags of Wq/Wk/Wv (K pre-scaled by log2e) ----
    const int v0 = bid - 1024;        // 0..383
    const int nt = v0 >> 6;
    const int lane = t & 63;
    const int hk = (v0 & 63) * 4 + (t >> 6);
    const int h = hk >> 4, kc = hk & 15;
    const int which = nt >> 1;
    const float* Wx = which == 0 ? Wq : (which == 1 ? Wk : Wv);
    const float scale = (which == 1) ? LOG2E : 1.0f;
    const int dd = (nt & 1) * 16 + (lane & 15);
    const int o0 = kc * 32 + (lane >> 4) * 8;
    s8v v;
#pragma unroll
    for (int j = 0; j < 8; j++)
      v[j] = (short)f2bf(Wx[((size_t)(h * INn + o0 + j)) * HDn + dd] * scale);
    ((s8v*)wxb)[((h * 16 + kc) * 6 + nt) * 64 + lane] = v;
  } else {
    // ---- beff ----
    const int v0 = bid - 1408;        // 0..47
    const int h = v0 & 15, which = v0 >> 4;
    const float* Wx = which == 0 ? Wq : (which == 1 ? Wk : Wv);
    const float scale = (which == 1) ? LOG2E : 1.0f;
    const int d = t & 31, oc = t >> 5;
    float p = 0.f;
    for (int k = 0; k < 64; k++) {
      int o = oc * 64 + k;
      p += bl[h * INn + o] * Wx[(h * INn + o) * HDn + d];
    }
    lds[t] = p;
    __syncthreads();
    if (t < 32) {
      float s = 0.f;
#pragma unroll
      for (int k = 0; k < 8; k++) s += lds[t + 32 * k];
      beff[which * (Hn * HDn) + h * HDn + t] = s * scale;
    }
  }
}

// ========== midphase: weff MFMA + xconv + woconv + barrier-counter zero (1408) ==========
__global__ __launch_bounds__(256)
void midphase_kernel(const unsigned short* __restrict__ wla_u,
                     const unsigned short* __restrict__ wxb_u,
                     unsigned short* __restrict__ wbb,
                     const float* __restrict__ x, unsigned short* __restrict__ xb,
                     const float* __restrict__ Wo, unsigned short* __restrict__ wob,
                     unsigned int* __restrict__ cnt) {
  const int bid = blockIdx.x;
  const int t = threadIdx.x;
  __shared__ unsigned short clds[32 * 97];
  if (bid < 256) {
    const int bx = bid & 15, h = bid >> 4;
    const int lane = t & 63, w = t >> 6;
    const int n = lane & 15, quad = lane >> 4;
    const int it16 = bx * 2 + (w & 1);
    const int nt0 = (w >> 1) * 3;
    const s8v* wlav = (const s8v*)wla_u;
    const s8v* wxbv = (const s8v*)wxb_u;
    f4v acc[3] = {};
#pragma unroll 4
    for (int kc = 0; kc < 16; ++kc) {
      s8v a = wlav[((h * 32 + it16) * 16 + kc) * 64 + lane];
      const s8v* wp = wxbv + (size_t)((h * 16 + kc) * 6 + nt0) * 64 + lane;
#pragma unroll
      for (int q = 0; q < 3; ++q)
        acc[q] = __builtin_amdgcn_mfma_f32_16x16x32_bf16(a, wp[q * 64], acc[q], 0, 0, 0);
    }
#pragma unroll
    for (int q = 0; q < 3; ++q)
#pragma unroll
      for (int reg = 0; reg < 4; ++reg) {
        int i_local = (w & 1) * 16 + quad * 4 + reg;
        int n96 = (nt0 + q) * 16 + n;
        clds[i_local * 97 + n96] = f2bf(acc[q][reg]);
      }
    __syncthreads();
    s8v* wbbv = (s8v*)wbb;
    for (int nt = w; nt < 6; nt += 4) {
      s8v v;
#pragma unroll
      for (int j = 0; j < 8; j++)
        v[j] = (short)clds[((lane >> 4) * 8 + j) * 97 + nt * 16 + (lane & 15)];
      wbbv[((h * 16 + bx) * 6 + nt) * 64 + lane] = v;
    }
  } else if (bid < 1280) {
    // ---- xconv ----
    const int tid = (bid - 256) * 256 + t;
    const int lane = tid & 63;
    const int rk = tid >> 6;
    const int rt16 = rk >> 4, kc = rk & 15;
    const float* src = x + (size_t)(rt16 * 16 + (lane & 15)) * INn + kc * 32 + (lane >> 4) * 8;
    unsigned short* dst = xb + (size_t)tid * 8;
#pragma unroll
    for (int j = 0; j < 8; j++) dst[j] = f2bf(src[j]);
  } else {
    // ---- woconv (+ zero group-barrier counters, one per 128B line) ----
    if (bid == 1280 && t < 32) cnt[t * CNT_STRIDE] = 0;
    const int tid = (bid - 1280) * 256 + t;
    const int lane = tid & 63;
    const int kn = tid >> 6;
    const int kc = kn >> 5, nt = kn & 31;
    const float* src = Wo + (size_t)(nt * 16 + (lane & 15)) * INn + kc * 32 + (lane >> 4) * 8;
    unsigned short* dst = wob + (size_t)tid * 8;
#pragma unroll
    for (int j = 0; j < 8; j++) dst[j] = f2bf(src[j]);
  }
}

// ---------------- fused qkv+attn helpers ----------------
__device__ __forceinline__ void qkv_epilogue(
    const f4v (&acc)[6], int qslot, int qt, int bh, int h,
    int w, int n, int quad, int t,
    const float* __restrict__ beff, unsigned short* q_sh,
    unsigned short* scratch, unsigned short* __restrict__ kv) {
#pragma unroll
  for (int nt = 0; nt < 6; ++nt) {
    const int which = nt >> 1;
    const int dd = (nt & 1) * 16 + n;
    const float bias = beff[which * 512 + h * 32 + dd];
#pragma unroll
    for (int reg = 0; reg < 4; ++reg) {
      const int kl = w * 16 + quad * 4 + reg;
      unsigned short val = f2bf(acc[nt][reg] + bias);
      if (which == 0) {
        int off = (((kl >> 4) * 4 + (dd >> 3)) * 16 + (kl & 15)) * 8 + (dd & 7);
        q_sh[qslot * 2048 + off] = val;          // Q stays in LDS
      } else if (which == 1) {
        int f = ((kl >> 5) << 1) | ((kl >> 2) & 1);
        int mm = ((kl >> 3) & 3) * 4 + (kl & 3);
        int off = ((f * 4 + (dd >> 3)) * 16 + mm) * 8 + (dd & 7);
        scratch[off] = val;
      } else {
        int off = ((((kl >> 5) * 2 + (dd >> 4)) * 4 + ((kl >> 3) & 3)) * 16 + (dd & 15)) * 8 + (kl & 7);
        scratch[2048 + off] = val;
      }
    }
  }
  __syncthreads();
  const size_t tilebase = ((size_t)bh * 32 + qt) * 2048;
  s8v* Kd = (s8v*)(kv + tilebase);
  s8v* Vd = (s8v*)(kv + (size_t)NQ + tilebase);
  const s8v* sv = (const s8v*)scratch;
  Kd[t] = sv[t];
  Vd[t] = sv[256 + t];
}

__device__ __forceinline__ void tile_step(
    bool diag, int w, int n, int quad,
    const s8v& qf, const s8v& kf0, const s8v& kf1, const s8v& kf2, const s8v& kf3,
    const s8v& vf00, const s8v& vf01, const s8v& vf10, const s8v& vf11,
    float& lp, f4v& O0, f4v& O1) {
  const f4v zero{};
  f4v s0 = __builtin_amdgcn_mfma_f32_16x16x32_bf16(kf0, qf, zero, 0, 0, 0);
  f4v s1 = __builtin_amdgcn_mfma_f32_16x16x32_bf16(kf1, qf, zero, 0, 0, 0);
  f4v s2 = __builtin_amdgcn_mfma_f32_16x16x32_bf16(kf2, qf, zero, 0, 0, 0);
  f4v s3 = __builtin_amdgcn_mfma_f32_16x16x32_bf16(kf3, qf, zero, 0, 0, 0);
  float p[16];
#pragma unroll
  for (int r = 0; r < 4; ++r) {
    p[0 * 4 + r] = s0[r];
    p[1 * 4 + r] = s1[r];
    p[2 * 4 + r] = s2[r];
    p[3 * 4 + r] = s3[r];
  }
  if (diag) {
    int qa = w * 16 + n;
#pragma unroll
    for (int f = 0; f < 4; ++f)
#pragma unroll
      for (int r = 0; r < 4; ++r) {
        int ka = ((f >> 1) << 5) + quad * 8 + ((f & 1) << 2) + r;
        if (ka > qa) p[f * 4 + r] = -1e30f;
      }
  }
#pragma unroll
  for (int i = 0; i < 16; ++i) {
    p[i] = __builtin_amdgcn_exp2f(p[i]);   // scores pre-scaled by log2e; masked -> 0
    lp += p[i];
  }
  s8v pf0, pf1;
#pragma unroll
  for (int j = 0; j < 8; ++j) {
    pf0[j] = (short)f2bf(p[j]);
    pf1[j] = (short)f2bf(p[8 + j]);
  }
  O0 = __builtin_amdgcn_mfma_f32_16x16x32_bf16(pf0, vf00, O0, 0, 0, 0);
  O0 = __builtin_amdgcn_mfma_f32_16x16x32_bf16(pf1, vf10, O0, 0, 0, 0);
  O1 = __builtin_amdgcn_mfma_f32_16x16x32_bf16(pf0, vf01, O1, 0, 0, 0);
  O1 = __builtin_amdgcn_mfma_f32_16x16x32_bf16(pf1, vf11, O1, 0, 0, 0);
}

__device__ __forceinline__ void attn_write(
    unsigned short* __restrict__ fb, int bh, int qt, int w, int n, int quad,
    float l, const f4v& O0, const f4v& O1) {
  float linv = 1.f / l;
  const int b = bh >> 4, h = bh & 15;
#pragma unroll
  for (int r = 0; r < 4; ++r) {
    float lr = __shfl(linv, quad * 4 + r, 64);
    int qabs = qt * 64 + w * 16 + quad * 4 + r;
    int rglob = b * 2048 + qabs;
    int rt16 = rglob >> 4, m = rglob & 15;
    size_t base = (size_t)(rt16 * 16 + h) * 512;
    fb[base + ((n >> 3) * 16 + m) * 8 + (n & 7)] = f2bf(O0[r] * lr);
    fb[base + ((2 + (n >> 3)) * 16 + m) * 8 + (n & 7)] = f2bf(O1[r] * lr);
  }
}

// ================= fused QKV + flash attention (per-(b,h) group barrier) =================
// grid (16, 32): x = q-tile pair (qp, 31-qp), y = bh. 16 blocks per bh group.
// Barrier: padded per-group counters (128B apart); poll = device-scope atomic LOAD
// (no RMW -> no exclusive-line convoy); release = fetch_add(RELEASE).
__global__ __launch_bounds__(256, 2)
void qkv_attn_kernel(const unsigned short* __restrict__ xb_u,
                     const unsigned short* __restrict__ wbb_u,
                     const float* __restrict__ beff,
                     unsigned short* __restrict__ kv,
                     unsigned int* __restrict__ cnt,
                     unsigned short* __restrict__ fb) {
  const int qp = blockIdx.x, bh = blockIdx.y;
  const int qtA = qp, qtB = 31 - qp;
  const int b = bh >> 4, h = bh & 15;
  const int t = threadIdx.x;
  const int lane = t & 63, w = t >> 6;
  const int n = lane & 15, quad = lane >> 4;
  __shared__ __align__(16) unsigned short q_sh[2 * 2048];   // Q tiles A,B (never to global)
  __shared__ __align__(16) unsigned short scratch[8192];    // phase1: K/V eld; phase2: k/v dbuf

  // ---- phase 1: project both q-tiles in one pass over the B operand ----
  {
    const s8v* xbv = (const s8v*)xb_u;
    const s8v* wbbv = (const s8v*)wbb_u;
    const int rtA = (b * 32 + qtA) * 4 + w;
    const int rtB = (b * 32 + qtB) * 4 + w;
    f4v accA[6] = {}, accB[6] = {};
#pragma unroll 2
    for (int kc = 0; kc < 16; ++kc) {
      s8v aA = xbv[(rtA * 16 + kc) * 64 + lane];
      s8v aB = xbv[(rtB * 16 + kc) * 64 + lane];
      const s8v* wp = wbbv + (size_t)((h * 16 + kc) * 6) * 64 + lane;
#pragma unroll
      for (int nt = 0; nt < 6; ++nt) {
        s8v bb = wp[nt * 64];
        accA[nt] = __builtin_amdgcn_mfma_f32_16x16x32_bf16(aA, bb, accA[nt], 0, 0, 0);
        accB[nt] = __builtin_amdgcn_mfma_f32_16x16x32_bf16(aB, bb, accB[nt], 0, 0, 0);
      }
    }
    qkv_epilogue(accA, 0, qtA, bh, h, w, n, quad, t, beff, q_sh, scratch, kv);
    __syncthreads();   // eld reads done before reuse
    qkv_epilogue(accB, 1, qtB, bh, h, w, n, quad, t, beff, q_sh, scratch, kv);
  }

  // ---- group barrier ----
  __syncthreads();                       // all K/V stores issued (syncthreads drains vmcnt)
  unsigned int* my_cnt = cnt + bh * CNT_STRIDE;
  if (t == 0) {
    __threadfence();                     // release: K/V visible device-wide
    __hip_atomic_fetch_add(my_cnt, 1u, __ATOMIC_RELEASE, __HIP_MEMORY_SCOPE_AGENT);
    int guard = 0;
    while (__hip_atomic_load(my_cnt, __ATOMIC_ACQUIRE, __HIP_MEMORY_SCOPE_AGENT) < 16u &&
           guard < (1 << 20)) {
      __builtin_amdgcn_s_sleep(16);
      ++guard;
    }
  }
  __syncthreads();
  __threadfence();                       // acquire: invalidate stale cache lines

  // ---- phase 2: flash attention, double-buffered K/V, one barrier per tile ----
  {
    const s8v* Ks = (const s8v*)kv + (size_t)bh * 32 * 256;
    const s8v* Vs = (const s8v*)(kv + (size_t)NQ) + (size_t)bh * 32 * 256;
    s8v* kvbuf = (s8v*)scratch;          // [2][k:256 | v:256]
    const s8v* qshv = (const s8v*)q_sh;
    s8v qfA = qshv[w * 64 + lane];
    s8v qfB = qshv[256 + w * 64 + lane];
    f4v OA0{}, OA1{}, OB0{}, OB1{};
    float lpA = 0.f, lpB = 0.f;
    s8v kpre = Ks[t];
    s8v vpre = Vs[t];
    for (int kt = 0; kt <= qtB; ++kt) {
      const int c = kt & 1;
      kvbuf[c * 512 + t] = kpre;
      kvbuf[c * 512 + 256 + t] = vpre;
      __syncthreads();
      if (kt < qtB) {
        kpre = Ks[(kt + 1) * 256 + t];
        vpre = Vs[(kt + 1) * 256 + t];
      }
      const s8v* kb = kvbuf + c * 512;
      const s8v* vb = kb + 256;
      s8v kf0 = kb[lane], kf1 = kb[64 + lane], kf2 = kb[128 + lane], kf3 = kb[192 + lane];
      s8v vf00 = vb[lane], vf01 = vb[64 + lane], vf10 = vb[128 + lane], vf11 = vb[192 + lane];
      if (kt <= qtA)
        tile_step(kt == qtA, w, n, quad, qfA, kf0, kf1, kf2, kf3,
                  vf00, vf01, vf10, vf11, lpA, OA0, OA1);
      tile_step(kt == qtB, w, n, quad, qfB, kf0, kf1, kf2, kf3,
                vf00, vf01, vf10, vf11, lpB, OB0, OB1);
    }
    lpA += __shfl_xor(lpA, 16); lpA += __shfl_xor(lpA, 32);
    lpB += __shfl_xor(lpB, 16); lpB += __shfl_xor(lpB, 32);
    attn_write(fb, bh, qtA, w, n, quad, lpA, OA0, OA1);
    attn_write(fb, bh, qtB, w, n, quad, lpB, OB0, OB1);
  }
}

// ================= output projection: zero-LDS MFMA GEMM =================
__global__ __launch_bounds__(256)
void outproj_mfma_kernel(const unsigned short* __restrict__ fb_u,
                         const unsigned short* __restrict__ wob_u,
                         const float* __restrict__ bo,
                         float* __restrict__ out) {
  const int rt64 = blockIdx.x;  // 64
  const int jt = blockIdx.y;    // 4
  const int t = threadIdx.x;
  const int lane = t & 63, w = t >> 6;
  const int n = lane & 15, quad = lane >> 4;
  const s8v* fbv = (const s8v*)fb_u;
  const s8v* wobv = (const s8v*)wob_u;
  const int rt16 = rt64 * 4 + w;
  f4v acc[8] = {};
#pragma unroll 2
  for (int kc = 0; kc < 16; ++kc) {
    s8v a = fbv[(rt16 * 16 + kc) * 64 + lane];
    const s8v* wp = wobv + (size_t)(kc * 32 + jt * 8) * 64 + lane;
#pragma unroll
    for (int i = 0; i < 8; ++i)
      acc[i] = __builtin_amdgcn_mfma_f32_16x16x32_bf16(a, wp[i * 64], acc[i], 0, 0, 0);
  }
#pragma unroll
  for (int i = 0; i < 8; ++i) {
    const int j = jt * 128 + i * 16 + n;
    const float bias = bo[j];
#pragma unroll
    for (int reg = 0; reg < 4; ++reg) {
      int r = rt64 * 64 + w * 16 + quad * 4 + reg;
      out[(size_t)r * INn + j] = acc[i][reg] + bias;
    }
  }
}

extern "C" void kernel_launch(void* const* d_in, const int* in_sizes, int n_in,
                              void* d_out, int out_size, void* d_ws, size_t ws_size,
                              hipStream_t stream) {
  const float* x  = (const float*)d_in[0];
  const float* Wl = (const float*)d_in[1];
  const float* bl = (const float*)d_in[2];
  const float* Wq = (const float*)d_in[3];
  const float* Wk = (const float*)d_in[4];
  const float* Wv = (const float*)d_in[5];
  const float* Wo = (const float*)d_in[6];
  const float* bo = (const float*)d_in[7];
  float* ws = (float*)d_ws;
  float* out = (float*)d_out;
  unsigned short* wla = (unsigned short*)(ws + OFF_WLA);
  unsigned short* wxb = (unsigned short*)(ws + OFF_WXB);
  unsigned short* wbb = (unsigned short*)(ws + OFF_WBB);
  float*          beff = ws + OFF_BEFF;
  unsigned short* kv  = (unsigned short*)(ws + OFF_KV);
  unsigned int*   cnt = (unsigned int*)(ws + OFF_CNT);
  unsigned short* xb  = (unsigned short*)(ws + OFF_XB);
  unsigned short* fb  = (unsigned short*)(ws + OFF_FB);
  unsigned short* wob = (unsigned short*)(ws + OFF_WOB);

  prep_kernel<<<dim3(1456), 256, 0, stream>>>(Wl, bl, Wq, Wk, Wv, wla, wxb, beff);
  midphase_kernel<<<dim3(1408), 256, 0, stream>>>(wla, wxb, wbb, x, xb, Wo, wob, cnt);
  qkv_attn_kernel<<<dim3(16, 32), 256, 0, stream>>>(xb, wbb, beff, kv, cnt, fb);
  outproj_mfma_kernel<<<dim3(64, 4), 256, 0, stream>>>(fb, wob, bo, out);
}

// Round 10
// 148.690 us; speedup vs baseline: 2.7484x; 1.3457x over previous
//
#include <hip/hip_runtime.h>
#include <math.h>

namespace {
constexpr int Bn = 2, Sn = 2048, INn = 512, HDn = 32, Hn = 16;
constexpr int NQ = Bn * Hn * Sn * HDn;           // 2097152 bf16 elems per Q/K/V tensor
// ws offsets in FLOAT units — all regions DISJOINT
constexpr int OFF_WLA = 0;          // Wl A-frags bf16: 4194304 bf16 -> 2097152 fl
constexpr int OFF_WXB = 2097152;    // Wq/k/v B-frags bf16: 786432 bf16 -> 393216 fl
constexpr int OFF_WBB = 2490368;    // Weff B-frags bf16: 786432 bf16 -> 393216 fl
constexpr int OFF_BEFF = 2883584;   // 1536 fl
constexpr int OFF_QKV = 2885120;    // Q,K,V swizzled bf16: 3*2097152 -> 3145728 fl
constexpr int OFF_XB = 6030848;     // x A-frags bf16 -> 1048576 fl
constexpr int OFF_FB = 7079424;     // F A-frags bf16 -> 1048576 fl
constexpr int OFF_WOB = 8128000;    // Wo B-frags bf16 -> 131072 fl
constexpr float LOG2E = 1.44269504f;
}

typedef __attribute__((ext_vector_type(8))) short s8v;   // 8 bf16 in 4 VGPRs
typedef __attribute__((ext_vector_type(4))) float f4v;   // MFMA accumulator

__device__ __forceinline__ unsigned short f2bf(float x) {
  unsigned u = __float_as_uint(x);
  return (unsigned short)((u + 0x8000u) >> 16);
}

// ================= prep: wlconv + wxconv + beff (flat grid 1456) =================
__global__ __launch_bounds__(256)
void prep_kernel(const float* __restrict__ Wl, const float* __restrict__ bl,
                 const float* __restrict__ Wq, const float* __restrict__ Wk,
                 const float* __restrict__ Wv,
                 unsigned short* __restrict__ wla, unsigned short* __restrict__ wxb,
                 float* __restrict__ beff) {
  const int bid = blockIdx.x;
  const int t = threadIdx.x;
  __shared__ float lds[64 * 65];
  if (bid < 1024) {
    // ---- wlconv (LDS transpose): wla[h][it16][kc][lane][j] = Wl[h][o][i] ----
    const int it64 = bid & 7, ot64 = (bid >> 3) & 7, h = bid >> 6;
#pragma unroll
    for (int k = 0; k < 16; k++) {
      int idx = t + k * 256;
      lds[(idx >> 6) * 65 + (idx & 63)] =
          Wl[((size_t)(h * INn + ot64 * 64 + (idx >> 6))) * INn + it64 * 64 + (idx & 63)];
    }
    __syncthreads();
    const int itsub = t >> 6, lane = t & 63;
    const int n = lane & 15, quad = lane >> 4;
    s8v* wlav = (s8v*)wla;
#pragma unroll
    for (int kcsub = 0; kcsub < 2; kcsub++) {
      s8v v;
#pragma unroll
      for (int j = 0; j < 8; j++)
        v[j] = (short)f2bf(lds[(kcsub * 32 + quad * 8 + j) * 65 + itsub * 16 + n]);
      wlav[((h * 32 + it64 * 4 + itsub) * 16 + ot64 * 2 + kcsub) * 64 + lane] = v;
    }
  } else if (bid < 1408) {
    // ---- wxconv: B-frags of Wq/Wk/Wv (K pre-scaled by log2e) ----
    const int v0 = bid - 1024;        // 0..383
    const int nt = v0 >> 6;
    const int lane = t & 63;
    const int hk = (v0 & 63) * 4 + (t >> 6);
    const int h = hk >> 4, kc = hk & 15;
    const int which = nt >> 1;
    const float* Wx = which == 0 ? Wq : (which == 1 ? Wk : Wv);
    const float scale = (which == 1) ? LOG2E : 1.0f;
    const int dd = (nt & 1) * 16 + (lane & 15);
    const int o0 = kc * 32 + (lane >> 4) * 8;
    s8v v;
#pragma unroll
    for (int j = 0; j < 8; j++)
      v[j] = (short)f2bf(Wx[((size_t)(h * INn + o0 + j)) * HDn + dd] * scale);
    ((s8v*)wxb)[((h * 16 + kc) * 6 + nt) * 64 + lane] = v;
  } else {
    // ---- beff ----
    const int v0 = bid - 1408;        // 0..47
    const int h = v0 & 15, which = v0 >> 4;
    const float* Wx = which == 0 ? Wq : (which == 1 ? Wk : Wv);
    const float scale = (which == 1) ? LOG2E : 1.0f;
    const int d = t & 31, oc = t >> 5;
    float p = 0.f;
    for (int k = 0; k < 64; k++) {
      int o = oc * 64 + k;
      p += bl[h * INn + o] * Wx[(h * INn + o) * HDn + d];
    }
    lds[t] = p;
    __syncthreads();
    if (t < 32) {
      float s = 0.f;
#pragma unroll
      for (int k = 0; k < 8; k++) s += lds[t + 32 * k];
      beff[which * (Hn * HDn) + h * HDn + t] = s * scale;
    }
  }
}

// ========== midphase: weff MFMA (B-frag out) + xconv + woconv (flat 1408) ==========
__global__ __launch_bounds__(256)
void midphase_kernel(const unsigned short* __restrict__ wla_u,
                     const unsigned short* __restrict__ wxb_u,
                     unsigned short* __restrict__ wbb,
                     const float* __restrict__ x, unsigned short* __restrict__ xb,
                     const float* __restrict__ Wo, unsigned short* __restrict__ wob) {
  const int bid = blockIdx.x;
  const int t = threadIdx.x;
  __shared__ unsigned short clds[32 * 97];
  if (bid < 256) {
    const int bx = bid & 15, h = bid >> 4;
    const int lane = t & 63, w = t >> 6;
    const int n = lane & 15, quad = lane >> 4;
    const int it16 = bx * 2 + (w & 1);
    const int nt0 = (w >> 1) * 3;
    const s8v* wlav = (const s8v*)wla_u;
    const s8v* wxbv = (const s8v*)wxb_u;
    f4v acc[3] = {};
#pragma unroll 4
    for (int kc = 0; kc < 16; ++kc) {
      s8v a = wlav[((h * 32 + it16) * 16 + kc) * 64 + lane];
      const s8v* wp = wxbv + (size_t)((h * 16 + kc) * 6 + nt0) * 64 + lane;
#pragma unroll
      for (int q = 0; q < 3; ++q)
        acc[q] = __builtin_amdgcn_mfma_f32_16x16x32_bf16(a, wp[q * 64], acc[q], 0, 0, 0);
    }
#pragma unroll
    for (int q = 0; q < 3; ++q)
#pragma unroll
      for (int reg = 0; reg < 4; ++reg) {
        int i_local = (w & 1) * 16 + quad * 4 + reg;
        int n96 = (nt0 + q) * 16 + n;
        clds[i_local * 97 + n96] = f2bf(acc[q][reg]);
      }
    __syncthreads();
    s8v* wbbv = (s8v*)wbb;
    for (int nt = w; nt < 6; nt += 4) {
      s8v v;
#pragma unroll
      for (int j = 0; j < 8; j++)
        v[j] = (short)clds[((lane >> 4) * 8 + j) * 97 + nt * 16 + (lane & 15)];
      wbbv[((h * 16 + bx) * 6 + nt) * 64 + lane] = v;
    }
  } else if (bid < 1280) {
    // ---- xconv ----
    const int tid = (bid - 256) * 256 + t;      // 0..262143
    const int lane = tid & 63;
    const int rk = tid >> 6;
    const int rt16 = rk >> 4, kc = rk & 15;
    const float* src = x + (size_t)(rt16 * 16 + (lane & 15)) * INn + kc * 32 + (lane >> 4) * 8;
    unsigned short* dst = xb + (size_t)tid * 8;
#pragma unroll
    for (int j = 0; j < 8; j++) dst[j] = f2bf(src[j]);
  } else {
    // ---- woconv ----
    const int tid = (bid - 1280) * 256 + t;     // 0..32767
    const int lane = tid & 63;
    const int kn = tid >> 6;
    const int kc = kn >> 5, nt = kn & 31;
    const float* src = Wo + (size_t)(nt * 16 + (lane & 15)) * INn + kc * 32 + (lane >> 4) * 8;
    unsigned short* dst = wob + (size_t)tid * 8;
#pragma unroll
    for (int j = 0; j < 8; j++) dst[j] = f2bf(src[j]);
  }
}

// ================= QKV projection: zero-LDS-mainloop MFMA GEMM =================
__global__ __launch_bounds__(256)
void qkv_mfma_kernel(const unsigned short* __restrict__ xb_u,
                     const unsigned short* __restrict__ wbb_u,
                     const float* __restrict__ beff,
                     unsigned short* __restrict__ qkv) {
  const int rt64 = blockIdx.x;  // 64
  const int h = blockIdx.y;     // 16
  const int t = threadIdx.x;
  const int lane = t & 63, w = t >> 6;
  const int n = lane & 15, quad = lane >> 4;
  const s8v* xbv = (const s8v*)xb_u;
  const s8v* wbbv = (const s8v*)wbb_u;
  const int rt16 = rt64 * 4 + w;
  f4v acc[6] = {};
#pragma unroll 4
  for (int kc = 0; kc < 16; ++kc) {
    s8v a = xbv[(rt16 * 16 + kc) * 64 + lane];
    const s8v* wp = wbbv + (size_t)((h * 16 + kc) * 6) * 64 + lane;
#pragma unroll
    for (int nt = 0; nt < 6; ++nt)
      acc[nt] = __builtin_amdgcn_mfma_f32_16x16x32_bf16(a, wp[nt * 64], acc[nt], 0, 0, 0);
  }
  // epilogue: swizzled tiles assembled in LDS, then coalesced 16B stores
  __shared__ __align__(16) unsigned short eld[3 * 2048];
#pragma unroll
  for (int nt = 0; nt < 6; ++nt) {
    const int which = nt >> 1;
    const int dd = (nt & 1) * 16 + n;
    const float bias = beff[which * 512 + h * 32 + dd];
#pragma unroll
    for (int reg = 0; reg < 4; ++reg) {
      const int kl = w * 16 + quad * 4 + reg;
      unsigned short val = f2bf(acc[nt][reg] + bias);
      int off;
      if (which == 0) {
        off = (((kl >> 4) * 4 + (dd >> 3)) * 16 + (kl & 15)) * 8 + (dd & 7);
      } else if (which == 1) {
        int f = ((kl >> 5) << 1) | ((kl >> 2) & 1);
        int mm = ((kl >> 3) & 3) * 4 + (kl & 3);
        off = ((f * 4 + (dd >> 3)) * 16 + mm) * 8 + (dd & 7);
      } else {
        off = ((((kl >> 5) * 2 + (dd >> 4)) * 4 + ((kl >> 3) & 3)) * 16 + (dd & 15)) * 8 + (kl & 7);
      }
      eld[which * 2048 + off] = val;
    }
  }
  __syncthreads();
  const int b = rt64 >> 5;
  const int ts = rt64 & 31;
  const size_t tilebase = ((size_t)((b * Hn + h) * 32) + ts) * 2048;  // bf16 units
  const s8v* eldv = (const s8v*)eld;
#pragma unroll
  for (int c = 0; c < 3; ++c) {
    int idx = c * 256 + t;            // 0..767
    int which = idx >> 8, k8 = idx & 255;
    *((s8v*)(qkv + (size_t)which * NQ + tilebase) + k8) = eldv[idx];
  }
}

// ================= MFMA flash attention, fixed-base softmax =================
__device__ __forceinline__ void tile_step(
    bool diag, int w, int n, int quad,
    const s8v& qf, const s8v& kf0, const s8v& kf1, const s8v& kf2, const s8v& kf3,
    const s8v& vf00, const s8v& vf01, const s8v& vf10, const s8v& vf11,
    float& lp, f4v& O0, f4v& O1) {
  const f4v zero{};
  f4v s0 = __builtin_amdgcn_mfma_f32_16x16x32_bf16(kf0, qf, zero, 0, 0, 0);
  f4v s1 = __builtin_amdgcn_mfma_f32_16x16x32_bf16(kf1, qf, zero, 0, 0, 0);
  f4v s2 = __builtin_amdgcn_mfma_f32_16x16x32_bf16(kf2, qf, zero, 0, 0, 0);
  f4v s3 = __builtin_amdgcn_mfma_f32_16x16x32_bf16(kf3, qf, zero, 0, 0, 0);
  float p[16];
#pragma unroll
  for (int r = 0; r < 4; ++r) {
    p[0 * 4 + r] = s0[r];
    p[1 * 4 + r] = s1[r];
    p[2 * 4 + r] = s2[r];
    p[3 * 4 + r] = s3[r];
  }
  if (diag) {
    int qa = w * 16 + n;
#pragma unroll
    for (int f = 0; f < 4; ++f)
#pragma unroll
      for (int r = 0; r < 4; ++r) {
        int ka = ((f >> 1) << 5) + quad * 8 + ((f & 1) << 2) + r;
        if (ka > qa) p[f * 4 + r] = -1e30f;
      }
  }
#pragma unroll
  for (int i = 0; i < 16; ++i) {
    p[i] = __builtin_amdgcn_exp2f(p[i]);   // scores pre-scaled by log2e; masked -> 0
    lp += p[i];
  }
  s8v pf0, pf1;
#pragma unroll
  for (int j = 0; j < 8; ++j) {
    pf0[j] = (short)f2bf(p[j]);
    pf1[j] = (short)f2bf(p[8 + j]);
  }
  O0 = __builtin_amdgcn_mfma_f32_16x16x32_bf16(pf0, vf00, O0, 0, 0, 0);
  O0 = __builtin_amdgcn_mfma_f32_16x16x32_bf16(pf1, vf10, O0, 0, 0, 0);
  O1 = __builtin_amdgcn_mfma_f32_16x16x32_bf16(pf0, vf01, O1, 0, 0, 0);
  O1 = __builtin_amdgcn_mfma_f32_16x16x32_bf16(pf1, vf11, O1, 0, 0, 0);
}

__device__ __forceinline__ void attn_write(
    unsigned short* __restrict__ fb, int bh, int qt, int w, int n, int quad,
    float l, const f4v& O0, const f4v& O1) {
  float linv = 1.f / l;
  const int b = bh >> 4, h = bh & 15;
#pragma unroll
  for (int r = 0; r < 4; ++r) {
    float lr = __shfl(linv, quad * 4 + r, 64);
    int qabs = qt * 64 + w * 16 + quad * 4 + r;
    int rglob = b * 2048 + qabs;
    int rt16 = rglob >> 4, m = rglob & 15;
    size_t base = (size_t)(rt16 * 16 + h) * 512;
    fb[base + ((n >> 3) * 16 + m) * 8 + (n & 7)] = f2bf(O0[r] * lr);
    fb[base + ((2 + (n >> 3)) * 16 + m) * 8 + (n & 7)] = f2bf(O1[r] * lr);
  }
}

// grid (16,32): paired q-tiles (qp, 31-qp); direct-global Q frags; dbuf K/V LDS,
// one barrier per k-tile; 2-deep register prefetch pipeline.
__global__ __launch_bounds__(256, 2)
void attn_kernel(const unsigned short* __restrict__ qkv_bf, unsigned short* __restrict__ fb) {
  const int qp = blockIdx.x;   // 0..15
  const int bh = blockIdx.y;   // 0..31
  const int qtA = qp, qtB = 31 - qp;
  const int t = threadIdx.x;
  const int lane = t & 63, w = t >> 6;
  const int n = lane & 15, quad = lane >> 4;
  __shared__ s8v kv_sh[2][512];   // [buf][k:256 | v:256] = 16 KB
  const s8v* Qs = (const s8v*)qkv_bf + (size_t)bh * 32 * 256;
  const s8v* Ks = (const s8v*)(qkv_bf + NQ) + (size_t)bh * 32 * 256;
  const s8v* Vs = (const s8v*)(qkv_bf + 2 * NQ) + (size_t)bh * 32 * 256;
  // pre-swizzled layout: direct coalesced fragment loads, no LDS staging for Q
  s8v qfA = Qs[qtA * 256 + w * 64 + lane];
  s8v qfB = Qs[qtB * 256 + w * 64 + lane];
  f4v OA0{}, OA1{}, OB0{}, OB1{};
  float lpA = 0.f, lpB = 0.f;
  // 2-deep prefetch pipeline
  s8v k0 = Ks[t], v0 = Vs[t];
  s8v k1, v1;
  if (qtB >= 1) { k1 = Ks[256 + t]; v1 = Vs[256 + t]; }
  for (int kt = 0; kt <= qtB; ++kt) {
    const int c = kt & 1;
    kv_sh[c][t] = k0;
    kv_sh[c][256 + t] = v0;
    __syncthreads();
    k0 = k1; v0 = v1;
    if (kt + 2 <= qtB) {
      k1 = Ks[(kt + 2) * 256 + t];
      v1 = Vs[(kt + 2) * 256 + t];
    }
    const s8v* kb = kv_sh[c];
    const s8v* vb = kb + 256;
    s8v kf0 = kb[lane], kf1 = kb[64 + lane], kf2 = kb[128 + lane], kf3 = kb[192 + lane];
    s8v vf00 = vb[lane], vf01 = vb[64 + lane], vf10 = vb[128 + lane], vf11 = vb[192 + lane];
    if (kt <= qtA)
      tile_step(kt == qtA, w, n, quad, qfA, kf0, kf1, kf2, kf3,
                vf00, vf01, vf10, vf11, lpA, OA0, OA1);
    tile_step(kt == qtB, w, n, quad, qfB, kf0, kf1, kf2, kf3,
              vf00, vf01, vf10, vf11, lpB, OB0, OB1);
  }
  lpA += __shfl_xor(lpA, 16); lpA += __shfl_xor(lpA, 32);
  lpB += __shfl_xor(lpB, 16); lpB += __shfl_xor(lpB, 32);
  attn_write(fb, bh, qtA, w, n, quad, lpA, OA0, OA1);
  attn_write(fb, bh, qtB, w, n, quad, lpB, OB0, OB1);
}

// ================= output projection: zero-LDS MFMA GEMM =================
__global__ __launch_bounds__(256)
void outproj_mfma_kernel(const unsigned short* __restrict__ fb_u,
                         const unsigned short* __restrict__ wob_u,
                         const float* __restrict__ bo,
                         float* __restrict__ out) {
  const int rt64 = blockIdx.x;  // 64
  const int jt = blockIdx.y;    // 4
  const int t = threadIdx.x;
  const int lane = t & 63, w = t >> 6;
  const int n = lane & 15, quad = lane >> 4;
  const s8v* fbv = (const s8v*)fb_u;
  const s8v* wobv = (const s8v*)wob_u;
  const int rt16 = rt64 * 4 + w;
  f4v acc[8] = {};
#pragma unroll 2
  for (int kc = 0; kc < 16; ++kc) {
    s8v a = fbv[(rt16 * 16 + kc) * 64 + lane];
    const s8v* wp = wobv + (size_t)(kc * 32 + jt * 8) * 64 + lane;
#pragma unroll
    for (int i = 0; i < 8; ++i)
      acc[i] = __builtin_amdgcn_mfma_f32_16x16x32_bf16(a, wp[i * 64], acc[i], 0, 0, 0);
  }
#pragma unroll
  for (int i = 0; i < 8; ++i) {
    const int j = jt * 128 + i * 16 + n;
    const float bias = bo[j];
#pragma unroll
    for (int reg = 0; reg < 4; ++reg) {
      int r = rt64 * 64 + w * 16 + quad * 4 + reg;
      out[(size_t)r * INn + j] = acc[i][reg] + bias;
    }
  }
}

extern "C" void kernel_launch(void* const* d_in, const int* in_sizes, int n_in,
                              void* d_out, int out_size, void* d_ws, size_t ws_size,
                              hipStream_t stream) {
  const float* x  = (const float*)d_in[0];
  const float* Wl = (const float*)d_in[1];
  const float* bl = (const float*)d_in[2];
  const float* Wq = (const float*)d_in[3];
  const float* Wk = (const float*)d_in[4];
  const float* Wv = (const float*)d_in[5];
  const float* Wo = (const float*)d_in[6];
  const float* bo = (const float*)d_in[7];
  float* ws = (float*)d_ws;
  float* out = (float*)d_out;
  unsigned short* wla = (unsigned short*)(ws + OFF_WLA);
  unsigned short* wxb = (unsigned short*)(ws + OFF_WXB);
  unsigned short* wbb = (unsigned short*)(ws + OFF_WBB);
  float*          beff = ws + OFF_BEFF;
  unsigned short* qkv = (unsigned short*)(ws + OFF_QKV);
  unsigned short* xb  = (unsigned short*)(ws + OFF_XB);
  unsigned short* fb  = (unsigned short*)(ws + OFF_FB);
  unsigned short* wob = (unsigned short*)(ws + OFF_WOB);

  prep_kernel<<<dim3(1456), 256, 0, stream>>>(Wl, bl, Wq, Wk, Wv, wla, wxb, beff);
  midphase_kernel<<<dim3(1408), 256, 0, stream>>>(wla, wxb, wbb, x, xb, Wo, wob);
  qkv_mfma_kernel<<<dim3(64, Hn), 256, 0, stream>>>(xb, wbb, beff, qkv);
  attn_kernel<<<dim3(16, 32), 256, 0, stream>>>(qkv, fb);
  outproj_mfma_kernel<<<dim3(64, 4), 256, 0, stream>>>(fb, wob, bo, out);
}

// Round 11
// 147.964 us; speedup vs baseline: 2.7619x; 1.0049x over previous
//
#include <hip/hip_runtime.h>
#include <math.h>

namespace {
constexpr int Bn = 2, Sn = 2048, INn = 512, HDn = 32, Hn = 16;
constexpr int NQ = Bn * Hn * Sn * HDn;           // 2097152 bf16 elems per Q/K/V tensor
// ws offsets in FLOAT units — all regions DISJOINT
constexpr int OFF_WBB = 2490368;    // Weff B-frags bf16: 786432 bf16 -> 393216 fl
constexpr int OFF_BEFF = 2883584;   // 1536 fl
constexpr int OFF_QKV = 2885120;    // Q,K,V swizzled bf16: 3*2097152 -> 3145728 fl
constexpr int OFF_XB = 6030848;     // x A-frags bf16 -> 1048576 fl
constexpr int OFF_FB = 7079424;     // F A-frags bf16 -> 1048576 fl
constexpr int OFF_WOB = 8128000;    // Wo B-frags bf16 -> 131072 fl
constexpr float LOG2E = 1.44269504f;
}

typedef __attribute__((ext_vector_type(8))) short s8v;   // 8 bf16 in 4 VGPRs
typedef __attribute__((ext_vector_type(4))) float f4v;   // MFMA accumulator

__device__ __forceinline__ unsigned short f2bf(float x) {
  unsigned u = __float_as_uint(x);
  return (unsigned short)((u + 0x8000u) >> 16);
}

// ========== K1: weff_direct (LDS-staged MFMA) + beff + xconv + woconv (flat 1456) ==========
// weff_direct block (bx 0..15, h): Weff rows i in [bx*32,+32), all 96 cols, K=512.
// Stages Wl transposed + Wx into LDS fragment layout per 64-o chunk; no global staging arrays.
__global__ __launch_bounds__(256)
void stage1_kernel(const float* __restrict__ Wl, const float* __restrict__ bl,
                   const float* __restrict__ Wq, const float* __restrict__ Wk,
                   const float* __restrict__ Wv,
                   const float* __restrict__ x, const float* __restrict__ Wo,
                   unsigned short* __restrict__ wbb, float* __restrict__ beff,
                   unsigned short* __restrict__ xb, unsigned short* __restrict__ wob) {
  const int bid = blockIdx.x;
  const int t = threadIdx.x;
  __shared__ __align__(16) unsigned short ws_sh[8192];   // 16 KB union
  if (bid < 256) {
    // ---- weff_direct ----
    const int bx = bid & 15, h = bid >> 4;
    const int lane = t & 63, w = t >> 6;
    const int n = lane & 15, quad = lane >> 4;
    const int nt0 = (w >> 1) * 3;
    unsigned short* a_sh = ws_sh;          // [4][512]  (it_sub*2+kc_sub)
    unsigned short* b_sh = ws_sh + 2048;   // [12][512] (kc_sub*6+nt)
    f4v acc[3] = {};
    for (int ot = 0; ot < 8; ++ot) {
      __syncthreads();   // previous chunk's reads done
      // stage A: Wl[h][o(64)][i(32)] -> transposed bf16 A-frags
#pragma unroll
      for (int k = 0; k < 8; ++k) {
        int idx = t + k * 256;
        int ol = idx >> 5, il = idx & 31;
        float v = Wl[(size_t)(h * INn + ot * 64 + ol) * INn + bx * 32 + il];
        int dst = (((il >> 4) * 2 + (ol >> 5)) * 64 + ((ol >> 3) & 3) * 16 + (il & 15)) * 8 + (ol & 7);
        a_sh[dst] = f2bf(v);
      }
      // stage B: Wq/Wk/Wv[h][o(64)][32] -> bf16 B-frags (K pre-scaled by log2e)
#pragma unroll
      for (int which = 0; which < 3; ++which) {
        const float* Wx = which == 0 ? Wq : (which == 1 ? Wk : Wv);
        const float scale = (which == 1) ? LOG2E : 1.0f;
#pragma unroll
        for (int k = 0; k < 8; ++k) {
          int idx = t + k * 256;
          int ol = idx >> 5, dd = idx & 31;
          float v = Wx[(size_t)(h * INn + ot * 64 + ol) * HDn + dd] * scale;
          int nt = which * 2 + (dd >> 4);
          int dst = (((ol >> 5) * 6 + nt) * 64 + ((ol >> 3) & 3) * 16 + (dd & 15)) * 8 + (ol & 7);
          b_sh[dst] = f2bf(v);
        }
      }
      __syncthreads();
      const s8v* av = (const s8v*)a_sh;
      const s8v* bv = (const s8v*)b_sh;
#pragma unroll
      for (int kc_sub = 0; kc_sub < 2; ++kc_sub) {
        s8v a = av[((w & 1) * 2 + kc_sub) * 64 + lane];
#pragma unroll
        for (int q = 0; q < 3; ++q)
          acc[q] = __builtin_amdgcn_mfma_f32_16x16x32_bf16(
              a, bv[(kc_sub * 6 + nt0 + q) * 64 + lane], acc[q], 0, 0, 0);
      }
    }
    // epilogue: C -> LDS (stride 97) -> B-frag coalesced stores
    __syncthreads();
    unsigned short* clds = ws_sh;   // 32*97 ushort
#pragma unroll
    for (int q = 0; q < 3; ++q)
#pragma unroll
      for (int reg = 0; reg < 4; ++reg) {
        int i_local = (w & 1) * 16 + quad * 4 + reg;
        int n96 = (nt0 + q) * 16 + n;
        clds[i_local * 97 + n96] = f2bf(acc[q][reg]);
      }
    __syncthreads();
    s8v* wbbv = (s8v*)wbb;
    for (int nt = w; nt < 6; nt += 4) {
      s8v v;
#pragma unroll
      for (int j = 0; j < 8; j++)
        v[j] = (short)clds[((lane >> 4) * 8 + j) * 97 + nt * 16 + (lane & 15)];
      wbbv[((h * 16 + bx) * 6 + nt) * 64 + lane] = v;
    }
  } else if (bid < 304) {
    // ---- beff ----
    const int v0 = bid - 256;         // 0..47
    const int h = v0 & 15, which = v0 >> 4;
    const float* Wx = which == 0 ? Wq : (which == 1 ? Wk : Wv);
    const float scale = (which == 1) ? LOG2E : 1.0f;
    const int d = t & 31, oc = t >> 5;
    float p = 0.f;
    for (int k = 0; k < 64; k++) {
      int o = oc * 64 + k;
      p += bl[h * INn + o] * Wx[(h * INn + o) * HDn + d];
    }
    float* red = (float*)ws_sh;
    red[t] = p;
    __syncthreads();
    if (t < 32) {
      float s = 0.f;
#pragma unroll
      for (int k = 0; k < 8; k++) s += red[t + 32 * k];
      beff[which * (Hn * HDn) + h * HDn + t] = s * scale;
    }
  } else if (bid < 1328) {
    // ---- xconv: x -> A-frags ----
    const int tid = (bid - 304) * 256 + t;      // 0..262143
    const int lane = tid & 63;
    const int rk = tid >> 6;
    const int rt16 = rk >> 4, kc = rk & 15;
    const float* src = x + (size_t)(rt16 * 16 + (lane & 15)) * INn + kc * 32 + (lane >> 4) * 8;
    unsigned short* dst = xb + (size_t)tid * 8;
#pragma unroll
    for (int j = 0; j < 8; j++) dst[j] = f2bf(src[j]);
  } else {
    // ---- woconv: Wo -> B-frags ----
    const int tid = (bid - 1328) * 256 + t;     // 0..32767
    const int lane = tid & 63;
    const int kn = tid >> 6;
    const int kc = kn >> 5, nt = kn & 31;
    const float* src = Wo + (size_t)(nt * 16 + (lane & 15)) * INn + kc * 32 + (lane >> 4) * 8;
    unsigned short* dst = wob + (size_t)tid * 8;
#pragma unroll
    for (int j = 0; j < 8; j++) dst[j] = f2bf(src[j]);
  }
}

// ================= K2: QKV projection: zero-LDS-mainloop MFMA GEMM =================
__global__ __launch_bounds__(256)
void qkv_mfma_kernel(const unsigned short* __restrict__ xb_u,
                     const unsigned short* __restrict__ wbb_u,
                     const float* __restrict__ beff,
                     unsigned short* __restrict__ qkv) {
  const int rt64 = blockIdx.x;  // 64
  const int h = blockIdx.y;     // 16
  const int t = threadIdx.x;
  const int lane = t & 63, w = t >> 6;
  const int n = lane & 15, quad = lane >> 4;
  const s8v* xbv = (const s8v*)xb_u;
  const s8v* wbbv = (const s8v*)wbb_u;
  const int rt16 = rt64 * 4 + w;
  f4v acc[6] = {};
#pragma unroll 4
  for (int kc = 0; kc < 16; ++kc) {
    s8v a = xbv[(rt16 * 16 + kc) * 64 + lane];
    const s8v* wp = wbbv + (size_t)((h * 16 + kc) * 6) * 64 + lane;
#pragma unroll
    for (int nt = 0; nt < 6; ++nt)
      acc[nt] = __builtin_amdgcn_mfma_f32_16x16x32_bf16(a, wp[nt * 64], acc[nt], 0, 0, 0);
  }
  // epilogue: swizzled tiles assembled in LDS, then coalesced 16B stores
  __shared__ __align__(16) unsigned short eld[3 * 2048];
#pragma unroll
  for (int nt = 0; nt < 6; ++nt) {
    const int which = nt >> 1;
    const int dd = (nt & 1) * 16 + n;
    const float bias = beff[which * 512 + h * 32 + dd];
#pragma unroll
    for (int reg = 0; reg < 4; ++reg) {
      const int kl = w * 16 + quad * 4 + reg;
      unsigned short val = f2bf(acc[nt][reg] + bias);
      int off;
      if (which == 0) {
        off = (((kl >> 4) * 4 + (dd >> 3)) * 16 + (kl & 15)) * 8 + (dd & 7);
      } else if (which == 1) {
        int f = ((kl >> 5) << 1) | ((kl >> 2) & 1);
        int mm = ((kl >> 3) & 3) * 4 + (kl & 3);
        off = ((f * 4 + (dd >> 3)) * 16 + mm) * 8 + (dd & 7);
      } else {
        off = ((((kl >> 5) * 2 + (dd >> 4)) * 4 + ((kl >> 3) & 3)) * 16 + (dd & 15)) * 8 + (kl & 7);
      }
      eld[which * 2048 + off] = val;
    }
  }
  __syncthreads();
  const int b = rt64 >> 5;
  const int ts = rt64 & 31;
  const size_t tilebase = ((size_t)((b * Hn + h) * 32) + ts) * 2048;  // bf16 units
  const s8v* eldv = (const s8v*)eld;
#pragma unroll
  for (int c = 0; c < 3; ++c) {
    int idx = c * 256 + t;            // 0..767
    int which = idx >> 8, k8 = idx & 255;
    *((s8v*)(qkv + (size_t)which * NQ + tilebase) + k8) = eldv[idx];
  }
}

// ================= K3: MFMA flash attention, fixed-base softmax =================
__device__ __forceinline__ void tile_step(
    bool diag, int w, int n, int quad,
    const s8v& qf, const s8v& kf0, const s8v& kf1, const s8v& kf2, const s8v& kf3,
    const s8v& vf00, const s8v& vf01, const s8v& vf10, const s8v& vf11,
    float& lp, f4v& O0, f4v& O1) {
  const f4v zero{};
  f4v s0 = __builtin_amdgcn_mfma_f32_16x16x32_bf16(kf0, qf, zero, 0, 0, 0);
  f4v s1 = __builtin_amdgcn_mfma_f32_16x16x32_bf16(kf1, qf, zero, 0, 0, 0);
  f4v s2 = __builtin_amdgcn_mfma_f32_16x16x32_bf16(kf2, qf, zero, 0, 0, 0);
  f4v s3 = __builtin_amdgcn_mfma_f32_16x16x32_bf16(kf3, qf, zero, 0, 0, 0);
  float p[16];
#pragma unroll
  for (int r = 0; r < 4; ++r) {
    p[0 * 4 + r] = s0[r];
    p[1 * 4 + r] = s1[r];
    p[2 * 4 + r] = s2[r];
    p[3 * 4 + r] = s3[r];
  }
  if (diag) {
    int qa = w * 16 + n;
#pragma unroll
    for (int f = 0; f < 4; ++f)
#pragma unroll
      for (int r = 0; r < 4; ++r) {
        int ka = ((f >> 1) << 5) + quad * 8 + ((f & 1) << 2) + r;
        if (ka > qa) p[f * 4 + r] = -1e30f;
      }
  }
#pragma unroll
  for (int i = 0; i < 16; ++i) {
    p[i] = __builtin_amdgcn_exp2f(p[i]);   // scores pre-scaled by log2e; masked -> 0
    lp += p[i];
  }
  s8v pf0, pf1;
#pragma unroll
  for (int j = 0; j < 8; ++j) {
    pf0[j] = (short)f2bf(p[j]);
    pf1[j] = (short)f2bf(p[8 + j]);
  }
  O0 = __builtin_amdgcn_mfma_f32_16x16x32_bf16(pf0, vf00, O0, 0, 0, 0);
  O0 = __builtin_amdgcn_mfma_f32_16x16x32_bf16(pf1, vf10, O0, 0, 0, 0);
  O1 = __builtin_amdgcn_mfma_f32_16x16x32_bf16(pf0, vf01, O1, 0, 0, 0);
  O1 = __builtin_amdgcn_mfma_f32_16x16x32_bf16(pf1, vf11, O1, 0, 0, 0);
}

__device__ __forceinline__ void attn_write(
    unsigned short* __restrict__ fb, int bh, int qt, int w, int n, int quad,
    float l, const f4v& O0, const f4v& O1) {
  float linv = 1.f / l;
  const int b = bh >> 4, h = bh & 15;
#pragma unroll
  for (int r = 0; r < 4; ++r) {
    float lr = __shfl(linv, quad * 4 + r, 64);
    int qabs = qt * 64 + w * 16 + quad * 4 + r;
    int rglob = b * 2048 + qabs;
    int rt16 = rglob >> 4, m = rglob & 15;
    size_t base = (size_t)(rt16 * 16 + h) * 512;
    fb[base + ((n >> 3) * 16 + m) * 8 + (n & 7)] = f2bf(O0[r] * lr);
    fb[base + ((2 + (n >> 3)) * 16 + m) * 8 + (n & 7)] = f2bf(O1[r] * lr);
  }
}

// grid (16,32): paired q-tiles (qp, 31-qp); direct-global Q frags; dbuf K/V LDS,
// one barrier per k-tile; 2-deep register prefetch pipeline.
__global__ __launch_bounds__(256, 2)
void attn_kernel(const unsigned short* __restrict__ qkv_bf, unsigned short* __restrict__ fb) {
  const int qp = blockIdx.x;   // 0..15
  const int bh = blockIdx.y;   // 0..31
  const int qtA = qp, qtB = 31 - qp;
  const int t = threadIdx.x;
  const int lane = t & 63, w = t >> 6;
  const int n = lane & 15, quad = lane >> 4;
  __shared__ s8v kv_sh[2][512];   // [buf][k:256 | v:256] = 16 KB
  const s8v* Qs = (const s8v*)qkv_bf + (size_t)bh * 32 * 256;
  const s8v* Ks = (const s8v*)(qkv_bf + NQ) + (size_t)bh * 32 * 256;
  const s8v* Vs = (const s8v*)(qkv_bf + 2 * NQ) + (size_t)bh * 32 * 256;
  s8v qfA = Qs[qtA * 256 + w * 64 + lane];
  s8v qfB = Qs[qtB * 256 + w * 64 + lane];
  f4v OA0{}, OA1{}, OB0{}, OB1{};
  float lpA = 0.f, lpB = 0.f;
  s8v k0 = Ks[t], v0 = Vs[t];
  s8v k1, v1;
  if (qtB >= 1) { k1 = Ks[256 + t]; v1 = Vs[256 + t]; }
  for (int kt = 0; kt <= qtB; ++kt) {
    const int c = kt & 1;
    kv_sh[c][t] = k0;
    kv_sh[c][256 + t] = v0;
    __syncthreads();
    k0 = k1; v0 = v1;
    if (kt + 2 <= qtB) {
      k1 = Ks[(kt + 2) * 256 + t];
      v1 = Vs[(kt + 2) * 256 + t];
    }
    const s8v* kb = kv_sh[c];
    const s8v* vb = kb + 256;
    s8v kf0 = kb[lane], kf1 = kb[64 + lane], kf2 = kb[128 + lane], kf3 = kb[192 + lane];
    s8v vf00 = vb[lane], vf01 = vb[64 + lane], vf10 = vb[128 + lane], vf11 = vb[192 + lane];
    if (kt <= qtA)
      tile_step(kt == qtA, w, n, quad, qfA, kf0, kf1, kf2, kf3,
                vf00, vf01, vf10, vf11, lpA, OA0, OA1);
    tile_step(kt == qtB, w, n, quad, qfB, kf0, kf1, kf2, kf3,
              vf00, vf01, vf10, vf11, lpB, OB0, OB1);
  }
  lpA += __shfl_xor(lpA, 16); lpA += __shfl_xor(lpA, 32);
  lpB += __shfl_xor(lpB, 16); lpB += __shfl_xor(lpB, 32);
  attn_write(fb, bh, qtA, w, n, quad, lpA, OA0, OA1);
  attn_write(fb, bh, qtB, w, n, quad, lpB, OB0, OB1);
}

// ================= K4: output projection: zero-LDS MFMA GEMM =================
__global__ __launch_bounds__(256)
void outproj_mfma_kernel(const unsigned short* __restrict__ fb_u,
                         const unsigned short* __restrict__ wob_u,
                         const float* __restrict__ bo,
                         float* __restrict__ out) {
  const int rt64 = blockIdx.x;  // 64
  const int jt = blockIdx.y;    // 4
  const int t = threadIdx.x;
  const int lane = t & 63, w = t >> 6;
  const int n = lane & 15, quad = lane >> 4;
  const s8v* fbv = (const s8v*)fb_u;
  const s8v* wobv = (const s8v*)wob_u;
  const int rt16 = rt64 * 4 + w;
  f4v acc[8] = {};
#pragma unroll 2
  for (int kc = 0; kc < 16; ++kc) {
    s8v a = fbv[(rt16 * 16 + kc) * 64 + lane];
    const s8v* wp = wobv + (size_t)(kc * 32 + jt * 8) * 64 + lane;
#pragma unroll
    for (int i = 0; i < 8; ++i)
      acc[i] = __builtin_amdgcn_mfma_f32_16x16x32_bf16(a, wp[i * 64], acc[i], 0, 0, 0);
  }
#pragma unroll
  for (int i = 0; i < 8; ++i) {
    const int j = jt * 128 + i * 16 + n;
    const float bias = bo[j];
#pragma unroll
    for (int reg = 0; reg < 4; ++reg) {
      int r = rt64 * 64 + w * 16 + quad * 4 + reg;
      out[(size_t)r * INn + j] = acc[i][reg] + bias;
    }
  }
}

extern "C" void kernel_launch(void* const* d_in, const int* in_sizes, int n_in,
                              void* d_out, int out_size, void* d_ws, size_t ws_size,
                              hipStream_t stream) {
  const float* x  = (const float*)d_in[0];
  const float* Wl = (const float*)d_in[1];
  const float* bl = (const float*)d_in[2];
  const float* Wq = (const float*)d_in[3];
  const float* Wk = (const float*)d_in[4];
  const float* Wv = (const float*)d_in[5];
  const float* Wo = (const float*)d_in[6];
  const float* bo = (const float*)d_in[7];
  float* ws = (float*)d_ws;
  float* out = (float*)d_out;
  unsigned short* wbb = (unsigned short*)(ws + OFF_WBB);
  float*          beff = ws + OFF_BEFF;
  unsigned short* qkv = (unsigned short*)(ws + OFF_QKV);
  unsigned short* xb  = (unsigned short*)(ws + OFF_XB);
  unsigned short* fb  = (unsigned short*)(ws + OFF_FB);
  unsigned short* wob = (unsigned short*)(ws + OFF_WOB);

  stage1_kernel<<<dim3(1456), 256, 0, stream>>>(Wl, bl, Wq, Wk, Wv, x, Wo, wbb, beff, xb, wob);
  qkv_mfma_kernel<<<dim3(64, Hn), 256, 0, stream>>>(xb, wbb, beff, qkv);
  attn_kernel<<<dim3(16, 32), 256, 0, stream>>>(qkv, fb);
  outproj_mfma_kernel<<<dim3(64, 4), 256, 0, stream>>>(fb, wob, bo, out);
}